// Round 3
// baseline (546.190 us; speedup 1.0000x reference)
//
#include <hip/hip_runtime.h>
#include <math.h>

#define NSQ 1024
#define DM  512
#define HDIM 64
#define TOPK 32
#define QSTR 72   // LDS stride for staged Q (16B-aligned, conflict-free frags)

typedef unsigned short u16;
typedef __attribute__((ext_vector_type(8))) short bf16x8;
typedef __attribute__((ext_vector_type(4))) float f32x4;

#define MFMA_B16(A,B,C) __builtin_amdgcn_mfma_f32_16x16x32_bf16(A,B,C,0,0,0)

__device__ __forceinline__ unsigned f2b(float x) {
    unsigned u = __float_as_uint(x);
    return (u + 0x7FFFu + ((u >> 16) & 1u)) >> 16;   // RN-even to bf16 bits
}
__device__ __forceinline__ float b2f(unsigned h) { return __uint_as_float(h << 16); }
__device__ __forceinline__ unsigned ordu(float f) {
    unsigned b = __float_as_uint(f);
    return b ^ (0x80000000u | (unsigned)((int)b >> 31));  // order-preserving uint
}

// ---------------------------------------------------------------------------
// fp32 [8192x512] x2 -> bf16 hi/lo planes (tgt -> T*, src -> S*)
// ---------------------------------------------------------------------------
__global__ __launch_bounds__(256) void conv2(
    const float* __restrict__ tgt, const float* __restrict__ src,
    u16* __restrict__ Thi, u16* __restrict__ Tlo,
    u16* __restrict__ Shi, u16* __restrict__ Slo)
{
    const int z = blockIdx.y;
    const float* x = z ? src : tgt;
    u16* hi = z ? Shi : Thi;
    u16* lo = z ? Slo : Tlo;
    int idx = blockIdx.x * 256 + threadIdx.x;
    float4 v = ((const float4*)x)[idx];
    float f[4] = {v.x, v.y, v.z, v.w};
    ushort4 hv, lv;
    unsigned h;
    h = f2b(f[0]); hv.x = (u16)h; lv.x = (u16)f2b(f[0] - b2f(h));
    h = f2b(f[1]); hv.y = (u16)h; lv.y = (u16)f2b(f[1] - b2f(h));
    h = f2b(f[2]); hv.z = (u16)h; lv.z = (u16)f2b(f[2] - b2f(h));
    h = f2b(f[3]); hv.w = (u16)h; lv.w = (u16)f2b(f[3] - b2f(h));
    ((ushort4*)hi)[idx] = hv;
    ((ushort4*)lo)[idx] = lv;
}

// ---------------------------------------------------------------------------
// All 5 weights [512,512] -> transposed bf16 hi/lo planes, one dispatch.
// planes layout: wsel -> hi at wsel*2*WPLANE, lo at +WPLANE
// ---------------------------------------------------------------------------
__global__ __launch_bounds__(256) void wconv5(
    const float* __restrict__ Wq, const float* __restrict__ Wk,
    const float* __restrict__ Wv, const float* __restrict__ W1,
    const float* __restrict__ W2, u16* __restrict__ planes)
{
    __shared__ float T[32][33];
    const int wsel = blockIdx.z;
    const float* W = (wsel == 0) ? Wq : (wsel == 1) ? Wk : (wsel == 2) ? Wv
                   : (wsel == 3) ? W1 : W2;
    u16* thi = planes + (size_t)wsel * 2 * DM * DM;
    u16* tlo = thi + (size_t)DM * DM;
    const int tx = threadIdx.x & 31, ty = threadIdx.x >> 5;
    const int n0 = blockIdx.x * 32, k0 = blockIdx.y * 32;
#pragma unroll
    for (int p = 0; p < 4; ++p) {
        int r = ty + p * 8;
        T[r][tx] = W[(size_t)(k0 + r) * DM + n0 + tx];
    }
    __syncthreads();
#pragma unroll
    for (int p = 0; p < 4; ++p) {
        int rr = ty + p * 8;
        float val = T[tx][rr];                       // = W[k0+tx][n0+rr]
        unsigned h = f2b(val);
        size_t off = (size_t)(n0 + rr) * DM + k0 + tx;
        thi[off] = (u16)h;
        tlo[off] = (u16)f2b(val - b2f(h));
    }
}

// ---------------------------------------------------------------------------
// C[8192,512] = act((Ahi+Alo) @ (Bhi+Blo)^T + bias)*scale (+R)
// 128x128 tile, 4 waves x (4x4 of 16x16x32 MFMA), BK=32.
// OUTMODE: 0 = fp32 (+R), 1 = bf16 hi+lo planes, 2 = bf16 hi only.
// ---------------------------------------------------------------------------
template<int SPLIT, int RELU, int OUTMODE>
__global__ __launch_bounds__(256) void mm512(
    const u16* __restrict__ Ah_g, const u16* __restrict__ Al_g,
    const u16* __restrict__ Bh_g, const u16* __restrict__ Bl_g,
    const float* __restrict__ bias, const float* __restrict__ R,
    float scale, float* __restrict__ outF,
    u16* __restrict__ outHi, u16* __restrict__ outLo)
{
    __shared__ u16 Ah[128 * 40], Bh[128 * 40];
    __shared__ u16 Al[SPLIT ? 128 * 40 : 8], Bl[SPLIT ? 128 * 40 : 8];
    const int tid = threadIdx.x, lane = tid & 63, w = tid >> 6;
    const int wr = (w >> 1) * 64, wc = (w & 1) * 64;
    const int ml = lane & 15, q8 = (lane >> 4) * 8, q4 = (lane >> 4) * 4;
    const int row0 = blockIdx.x * 128, col0 = blockIdx.y * 128;
    const int sm = tid >> 2, sk = (tid & 3) * 8;

    f32x4 acc[4][4];
#pragma unroll
    for (int i = 0; i < 4; ++i)
#pragma unroll
        for (int j = 0; j < 4; ++j) acc[i][j] = {0.f, 0.f, 0.f, 0.f};

    for (int k0 = 0; k0 < DM; k0 += 32) {
#pragma unroll
        for (int p = 0; p < 2; ++p) {
            int m = sm + p * 64;
            *(uint4*)&Ah[m * 40 + sk] = *(const uint4*)&Ah_g[(size_t)(row0 + m) * DM + k0 + sk];
            *(uint4*)&Bh[m * 40 + sk] = *(const uint4*)&Bh_g[(size_t)(col0 + m) * DM + k0 + sk];
            if (SPLIT) {
                *(uint4*)&Al[m * 40 + sk] = *(const uint4*)&Al_g[(size_t)(row0 + m) * DM + k0 + sk];
                *(uint4*)&Bl[m * 40 + sk] = *(const uint4*)&Bl_g[(size_t)(col0 + m) * DM + k0 + sk];
            }
        }
        __syncthreads();
        bf16x8 a_h[4], b_h[4], a_l[4], b_l[4];
#pragma unroll
        for (int i = 0; i < 4; ++i) {
            a_h[i] = *(const bf16x8*)&Ah[(wr + i * 16 + ml) * 40 + q8];
            b_h[i] = *(const bf16x8*)&Bh[(wc + i * 16 + ml) * 40 + q8];
            if (SPLIT) {
                a_l[i] = *(const bf16x8*)&Al[(wr + i * 16 + ml) * 40 + q8];
                b_l[i] = *(const bf16x8*)&Bl[(wc + i * 16 + ml) * 40 + q8];
            }
        }
#pragma unroll
        for (int i = 0; i < 4; ++i)
#pragma unroll
            for (int j = 0; j < 4; ++j) {
                acc[i][j] = MFMA_B16(a_h[i], b_h[j], acc[i][j]);
                if (SPLIT) {
                    acc[i][j] = MFMA_B16(a_h[i], b_l[j], acc[i][j]);
                    acc[i][j] = MFMA_B16(a_l[i], b_h[j], acc[i][j]);
                    acc[i][j] = MFMA_B16(a_l[i], b_l[j], acc[i][j]);
                }
            }
        __syncthreads();
    }

    float bcol[4];
#pragma unroll
    for (int j = 0; j < 4; ++j) bcol[j] = bias[col0 + wc + j * 16 + ml];
#pragma unroll
    for (int i = 0; i < 4; ++i)
#pragma unroll
        for (int j = 0; j < 4; ++j)
#pragma unroll
            for (int r = 0; r < 4; ++r) {
                int gm = row0 + wr + i * 16 + q4 + r;
                int gn = col0 + wc + j * 16 + ml;
                float t = acc[i][j][r] + bcol[j];
                if (RELU) t = fmaxf(t, 0.f);
                t *= scale;
                size_t off = (size_t)gm * DM + gn;
                if (OUTMODE == 0) {
                    if (R) t += R[off];
                    outF[off] = t;
                } else if (OUTMODE == 1) {
                    unsigned hb2 = f2b(t);
                    outHi[off] = (u16)hb2;
                    outLo[off] = (u16)f2b(t - b2f(hb2));
                } else {
                    outHi[off] = (u16)f2b(t);
                }
            }
}

// ---------------------------------------------------------------------------
// FUSED attention middle: per (16-row group, hb):
//  phase 1: S[16][1024] = q@k^T (split bf16, 4 combos) into LDS.
//           A-frags from LDS-staged Q; B-frags directly from global (L2).
//  phase 2: exact top-32 + softmax + PV gather, scores read from LDS.
// LDS ~71 KB -> 2 workgroups/CU.
// ---------------------------------------------------------------------------
__global__ __launch_bounds__(256, 2) void score_select(
    const u16* __restrict__ qhi, const u16* __restrict__ qlo,
    const u16* __restrict__ khi, const u16* __restrict__ klo,
    const u16* __restrict__ vhi, u16* __restrict__ ao)
{
    __shared__ float S[16 * NSQ];                 // 64 KB
    __shared__ u16 Qh[16 * QSTR], Ql[16 * QSTR];  // 2.25 KB each
    __shared__ float pv_[4][TOPK];
    __shared__ int   pi_[4][TOPK];

    const int tid = threadIdx.x, lane = tid & 63, w = tid >> 6;
    const int ml = lane & 15, q8 = (lane >> 4) * 8, q4 = (lane >> 4) * 4;
    const int hb = blockIdx.y, h = hb >> 3, b = hb & 7;
    const int r0 = blockIdx.x * 16;

    // ---- stage Q (16 rows x 64 dims, hi+lo planes) ----
    {
        int t2 = tid & 127, m = t2 >> 3, k8 = (t2 & 7) * 8;
        const u16* srcp = (tid < 128) ? qhi : qlo;
        u16* dst = (tid < 128) ? Qh : Ql;
        *(uint4*)&dst[m * QSTR + k8] =
            *(const uint4*)&srcp[((size_t)(b * NSQ + r0 + m)) * DM + h * HDIM + k8];
    }
    __syncthreads();

    // ---- phase 1: scores ----
    bf16x8 a_h0 = *(const bf16x8*)&Qh[ml * QSTR + q8];
    bf16x8 a_h1 = *(const bf16x8*)&Qh[ml * QSTR + 32 + q8];
    bf16x8 a_l0 = *(const bf16x8*)&Ql[ml * QSTR + q8];
    bf16x8 a_l1 = *(const bf16x8*)&Ql[ml * QSTR + 32 + q8];

    const u16* khp = khi + ((size_t)(b * NSQ + w * 256 + ml)) * DM + h * HDIM + q8;
    const u16* klp = klo + ((size_t)(b * NSQ + w * 256 + ml)) * DM + h * HDIM + q8;
    float* sbase = &S[q4 * NSQ + w * 256 + ml];

#pragma unroll 2
    for (int t = 0; t < 16; ++t) {
        bf16x8 bh0 = *(const bf16x8*)(khp);
        bf16x8 bh1 = *(const bf16x8*)(khp + 32);
        bf16x8 bl0 = *(const bf16x8*)(klp);
        bf16x8 bl1 = *(const bf16x8*)(klp + 32);
        f32x4 ac0 = {0.f, 0.f, 0.f, 0.f}, ac1 = {0.f, 0.f, 0.f, 0.f};
        ac0 = MFMA_B16(a_h0, bh0, ac0);
        ac0 = MFMA_B16(a_h1, bh1, ac0);
        ac0 = MFMA_B16(a_l0, bh0, ac0);
        ac0 = MFMA_B16(a_l1, bh1, ac0);
        ac1 = MFMA_B16(a_h0, bl0, ac1);
        ac1 = MFMA_B16(a_h1, bl1, ac1);
        ac1 = MFMA_B16(a_l0, bl0, ac1);
        ac1 = MFMA_B16(a_l1, bl1, ac1);
#pragma unroll
        for (int r = 0; r < 4; ++r)
            sbase[r * NSQ + t * 16] = ac0[r] + ac1[r];
        khp += 16 * DM;
        klp += 16 * DM;
    }
    __syncthreads();

    // ---- phase 2: per-row exact top-32 + softmax + PV ----
    const u16* vb = vhi + ((size_t)b * NSQ) * DM + h * HDIM + lane;
    for (int rr = 0; rr < 4; ++rr) {
        const int rloc = w * 4 + rr;
        const float* srow = &S[(size_t)rloc * NSQ];

        float f[16]; unsigned u[16];
        float s1 = 0.f, s2 = 0.f;
#pragma unroll
        for (int i = 0; i < 16; ++i) {
            f[i] = srow[i * 64 + lane];
            s1 += f[i];
            s2 = fmaf(f[i], f[i], s2);
        }
#pragma unroll
        for (int o = 32; o; o >>= 1) { s1 += __shfl_xor(s1, o); s2 += __shfl_xor(s2, o); }
        float mu = s1 * (1.f / 1024.f);
        float sg = sqrtf(fmaxf(s2 * (1.f / 1024.f) - mu * mu, 0.f)) + 1e-20f;
#pragma unroll
        for (int i = 0; i < 16; ++i) u[i] = ordu(f[i]);

        auto cnt = [&](unsigned t) -> int {
            int tot = 0;
#pragma unroll
            for (int i = 0; i < 16; ++i) tot += __popcll(__ballot(u[i] > t));
            return tot;
        };

        float tl = mu + 1.2f * sg, dstep = 0.7f * sg;
        unsigned lo = ordu(tl);
        int clo = cnt(lo);
        while (clo < TOPK) { tl -= dstep; dstep *= 2.f; lo = ordu(tl); clo = cnt(lo); }
        float th = mu + 4.0f * sg, ustep = 2.0f * sg;
        unsigned hi = ordu(th);
        int chi = cnt(hi);
        while (chi >= TOPK) { lo = hi; clo = chi; th += ustep; ustep *= 2.f; hi = ordu(th); chi = cnt(hi); }
        if (clo > TOPK) {
            while (hi - lo > 1u) {
                unsigned mid = lo + ((hi - lo) >> 1);
                int c = cnt(mid);
                if (c >= TOPK) { lo = mid; clo = c; if (c == TOPK) break; }
                else hi = mid;
            }
        }

        unsigned selm = 0;
#pragma unroll
        for (int i = 0; i < 16; ++i) if (u[i] > lo) selm |= (1u << i);

        // tie-prune at boundary value (drop largest col index first, = lax.top_k)
        int nsel = clo;
        unsigned bhi = lo + 1u;
        while (nsel > TOPK) {
            int myidx = -1, myslot = 0;
#pragma unroll
            for (int i = 0; i < 16; ++i)
                if (((selm >> i) & 1u) && u[i] == bhi) { myidx = i * 64 + lane; myslot = i; }
            int mx = myidx;
#pragma unroll
            for (int o = 32; o; o >>= 1) mx = max(mx, __shfl_xor(mx, o));
            if (myidx == mx && myidx >= 0) selm &= ~(1u << myslot);
            nsel--;
        }

        float lm = -INFINITY;
#pragma unroll
        for (int i = 0; i < 16; ++i) if ((selm >> i) & 1u) lm = fmaxf(lm, f[i]);
#pragma unroll
        for (int o = 32; o; o >>= 1) lm = fmaxf(lm, __shfl_xor(lm, o));
        float e[16], es = 0.f;
#pragma unroll
        for (int i = 0; i < 16; ++i) {
            e[i] = ((selm >> i) & 1u) ? __expf(f[i] - lm) : 0.f;
            es += e[i];
        }
#pragma unroll
        for (int o = 32; o; o >>= 1) es += __shfl_xor(es, o);
        float inv = 1.f / es;

        unsigned long long ltm = (1ull << lane) - 1ull;
        int basec = 0;
#pragma unroll
        for (int i = 0; i < 16; ++i) {
            unsigned long long m = __ballot((selm >> i) & 1u);
            if ((selm >> i) & 1u) {
                int slot = basec + __popcll(m & ltm);
                pv_[w][slot] = e[i] * inv;
                pi_[w][slot] = i * 64 + lane;
            }
            basec += __popcll(m);
        }
        // per-wave LDS buffer: compiler-inserted lgkmcnt orders write->read

        float acc = 0.f;
#pragma unroll 8
        for (int t = 0; t < TOPK; ++t)
            acc = fmaf(pv_[w][t], b2f(vb[(size_t)pi_[w][t] * DM]), acc);
        ao[((size_t)(b * NSQ + r0 + rloc)) * DM + h * HDIM + lane] = (u16)f2b(acc);
    }
}

// ---------------------------------------------------------------------------
// LayerNorm: out = LN(a [+ bf16 addb]) * g + be; optional fp32 + bf16-hi outs
// ---------------------------------------------------------------------------
__global__ __launch_bounds__(256) void ln_fused(
    const float* __restrict__ a, const u16* __restrict__ addb,
    const float* __restrict__ g, const float* __restrict__ be,
    float* __restrict__ outF, u16* __restrict__ outHi)
{
    __shared__ float red[4][2];
    const int row = blockIdx.x, tid = threadIdx.x, w = tid >> 6;
    float2 v = ((const float2*)(a + (size_t)row * DM))[tid];
    if (addb) {
        ushort2 ab = ((const ushort2*)(addb + (size_t)row * DM))[tid];
        v.x += b2f(ab.x); v.y += b2f(ab.y);
    }
    float s = v.x + v.y, q = v.x * v.x + v.y * v.y;
#pragma unroll
    for (int o = 32; o; o >>= 1) { s += __shfl_xor(s, o); q += __shfl_xor(q, o); }
    if ((tid & 63) == 0) { red[w][0] = s; red[w][1] = q; }
    __syncthreads();
    float S = red[0][0] + red[1][0] + red[2][0] + red[3][0];
    float Q = red[0][1] + red[1][1] + red[2][1] + red[3][1];
    float mu = S * (1.f / DM);
    float var = Q * (1.f / DM) - mu * mu;
    float rs = rsqrtf(var + 1e-5f);
    float2 gv = ((const float2*)g)[tid];
    float2 bv = ((const float2*)be)[tid];
    float2 o;
    o.x = (v.x - mu) * rs * gv.x + bv.x;
    o.y = (v.y - mu) * rs * gv.y + bv.y;
    if (outF) ((float2*)(outF + (size_t)row * DM))[tid] = o;
    if (outHi) {
        ushort2 hv; hv.x = (u16)f2b(o.x); hv.y = (u16)f2b(o.y);
        ((ushort2*)(outHi + (size_t)row * DM))[tid] = hv;
    }
}

// ---------------------------------------------------------------------------
extern "C" void kernel_launch(void* const* d_in, const int* in_sizes, int n_in,
                              void* d_out, int out_size, void* d_ws, size_t ws_size,
                              hipStream_t stream) {
    const float* src = (const float*)d_in[0];
    const float* tgt = (const float*)d_in[1];
    const float* Wq  = (const float*)d_in[2];
    const float* bq  = (const float*)d_in[3];
    const float* Wk  = (const float*)d_in[4];
    const float* bk  = (const float*)d_in[5];
    const float* Wv  = (const float*)d_in[6];
    const float* bv  = (const float*)d_in[7];
    const float* W1  = (const float*)d_in[8];
    const float* b1  = (const float*)d_in[9];
    const float* W2  = (const float*)d_in[10];
    const float* b2  = (const float*)d_in[11];
    const float* g1  = (const float*)d_in[12];
    const float* be1 = (const float*)d_in[13];
    const float* g2  = (const float*)d_in[14];
    const float* be2 = (const float*)d_in[15];

    // workspace map (MB offsets). Total footprint: 136 MB.
    const size_t WPLANE = (size_t)DM * DM;
    u16* planes = (u16*)d_ws;                    // 10 x 512 KB = 5 MB
    auto wh = [&](int i) { return planes + (size_t)i * 2 * WPLANE; };
    auto wl = [&](int i) { return planes + (size_t)i * 2 * WPLANE + WPLANE; };
    auto at = [&](size_t mb) { return (char*)d_ws + (mb << 20); };
    u16* Thi = (u16*)at(8);   u16* Tlo = (u16*)at(16);
    u16* Shi = (u16*)at(24);  u16* Slo = (u16*)at(32);
    u16* qhi = (u16*)at(40);  u16* qlo = (u16*)at(48);
    u16* khi = (u16*)at(56);  u16* klo = (u16*)at(64);
    u16* vhi = (u16*)at(72);
    u16* aob = (u16*)at(80);
    float* xb = (float*)at(88);                  // 16 MB fp32
    u16* xhi = (u16*)at(104);
    u16* hhi = (u16*)at(112);
    float* f2 = (float*)at(120);                 // 16 MB fp32

    dim3 blk(256);
    const float qscale = 0.04419417382415922f;   // 1/sqrt(512)

    wconv5<<<dim3(16, 16, 5), blk, 0, stream>>>(Wq, Wk, Wv, W1, W2, planes);
    conv2<<<dim3(4096, 2), blk, 0, stream>>>(tgt, src, Thi, Tlo, Shi, Slo);

    mm512<1, 0, 1><<<dim3(64, 4), blk, 0, stream>>>(Thi, Tlo, wh(0), wl(0), bq, nullptr,
                                                    qscale, nullptr, qhi, qlo);
    mm512<1, 0, 1><<<dim3(64, 4), blk, 0, stream>>>(Shi, Slo, wh(1), wl(1), bk, nullptr,
                                                    1.f, nullptr, khi, klo);
    mm512<0, 0, 2><<<dim3(64, 4), blk, 0, stream>>>(Shi, nullptr, wh(2), nullptr, bv, nullptr,
                                                    1.f, nullptr, vhi, nullptr);

    score_select<<<dim3(64, 64), blk, 0, stream>>>(qhi, qlo, khi, klo, vhi, aob);

    ln_fused<<<8192, blk, 0, stream>>>(tgt, aob, g1, be1, xb, xhi);
    mm512<0, 1, 2><<<dim3(64, 4), blk, 0, stream>>>(xhi, nullptr, wh(3), nullptr, b1, nullptr,
                                                    1.f, nullptr, hhi, nullptr);
    mm512<0, 0, 0><<<dim3(64, 4), blk, 0, stream>>>(hhi, nullptr, wh(4), nullptr, b2, xb,
                                                    1.f, f2, nullptr, nullptr);
    ln_fused<<<8192, blk, 0, stream>>>(f2, nullptr, g2, be2, (float*)d_out, nullptr);
}

// Round 5
// 527.203 us; speedup vs baseline: 1.0360x; 1.0360x over previous
//
#include <hip/hip_runtime.h>
#include <math.h>

#define NSQ 1024
#define DM  512
#define HDIM 64
#define TOPK 32
#define QSTR 72   // LDS stride for staged Q (16B-aligned, conflict-free frags)
#define PCAP 48   // candidate buffer capacity per row

typedef unsigned short u16;
typedef __attribute__((ext_vector_type(8))) short bf16x8;
typedef __attribute__((ext_vector_type(4))) float f32x4;

#define MFMA_B16(A,B,C) __builtin_amdgcn_mfma_f32_16x16x32_bf16(A,B,C,0,0,0)

__device__ __forceinline__ unsigned f2b(float x) {
    unsigned u = __float_as_uint(x);
    return (u + 0x7FFFu + ((u >> 16) & 1u)) >> 16;   // RN-even to bf16 bits
}
__device__ __forceinline__ float b2f(unsigned h) { return __uint_as_float(h << 16); }
__device__ __forceinline__ unsigned ordu(float f) {
    unsigned b = __float_as_uint(f);
    return b ^ (0x80000000u | (unsigned)((int)b >> 31));  // order-preserving uint
}
__device__ __forceinline__ float iordu(unsigned u) {
    unsigned b = (u & 0x80000000u) ? (u ^ 0x80000000u) : ~u;
    return __uint_as_float(b);
}

// ---------------------------------------------------------------------------
// fp32 [8192x512] x2 -> bf16 hi/lo planes (tgt -> T*, src -> S*)
// ---------------------------------------------------------------------------
__global__ __launch_bounds__(256) void conv2(
    const float* __restrict__ tgt, const float* __restrict__ src,
    u16* __restrict__ Thi, u16* __restrict__ Tlo,
    u16* __restrict__ Shi, u16* __restrict__ Slo)
{
    const int z = blockIdx.y;
    const float* x = z ? src : tgt;
    u16* hi = z ? Shi : Thi;
    u16* lo = z ? Slo : Tlo;
    int idx = blockIdx.x * 256 + threadIdx.x;
    float4 v = ((const float4*)x)[idx];
    float f[4] = {v.x, v.y, v.z, v.w};
    ushort4 hv, lv;
    unsigned h;
    h = f2b(f[0]); hv.x = (u16)h; lv.x = (u16)f2b(f[0] - b2f(h));
    h = f2b(f[1]); hv.y = (u16)h; lv.y = (u16)f2b(f[1] - b2f(h));
    h = f2b(f[2]); hv.z = (u16)h; lv.z = (u16)f2b(f[2] - b2f(h));
    h = f2b(f[3]); hv.w = (u16)h; lv.w = (u16)f2b(f[3] - b2f(h));
    ((ushort4*)hi)[idx] = hv;
    ((ushort4*)lo)[idx] = lv;
}

// ---------------------------------------------------------------------------
// All 5 weights [512,512] -> transposed bf16 hi/lo planes, one dispatch.
// ---------------------------------------------------------------------------
__global__ __launch_bounds__(256) void wconv5(
    const float* __restrict__ Wq, const float* __restrict__ Wk,
    const float* __restrict__ Wv, const float* __restrict__ W1,
    const float* __restrict__ W2, u16* __restrict__ planes)
{
    __shared__ float T[32][33];
    const int wsel = blockIdx.z;
    const float* W = (wsel == 0) ? Wq : (wsel == 1) ? Wk : (wsel == 2) ? Wv
                   : (wsel == 3) ? W1 : W2;
    u16* thi = planes + (size_t)wsel * 2 * DM * DM;
    u16* tlo = thi + (size_t)DM * DM;
    const int tx = threadIdx.x & 31, ty = threadIdx.x >> 5;
    const int n0 = blockIdx.x * 32, k0 = blockIdx.y * 32;
#pragma unroll
    for (int p = 0; p < 4; ++p) {
        int r = ty + p * 8;
        T[r][tx] = W[(size_t)(k0 + r) * DM + n0 + tx];
    }
    __syncthreads();
#pragma unroll
    for (int p = 0; p < 4; ++p) {
        int rr = ty + p * 8;
        float val = T[tx][rr];                       // = W[k0+tx][n0+rr]
        unsigned h = f2b(val);
        size_t off = (size_t)(n0 + rr) * DM + k0 + tx;
        thi[off] = (u16)h;
        tlo[off] = (u16)f2b(val - b2f(h));
    }
}

// ---------------------------------------------------------------------------
// C[8192,512] = act((Ahi+Alo) @ (Bhi+Blo)^T + bias)*scale (+R)
// 128x128 tile, 4 waves x (4x4 of 16x16x32 MFMA), BK=32.
// OUTMODE: 0 = fp32 (+R), 1 = bf16 hi+lo planes, 2 = bf16 hi only.
// ---------------------------------------------------------------------------
template<int SPLIT, int RELU, int OUTMODE>
__global__ __launch_bounds__(256) void mm512(
    const u16* __restrict__ Ah_g, const u16* __restrict__ Al_g,
    const u16* __restrict__ Bh_g, const u16* __restrict__ Bl_g,
    const float* __restrict__ bias, const float* __restrict__ R,
    float scale, float* __restrict__ outF,
    u16* __restrict__ outHi, u16* __restrict__ outLo)
{
    __shared__ u16 Ah[128 * 40], Bh[128 * 40];
    __shared__ u16 Al[SPLIT ? 128 * 40 : 8], Bl[SPLIT ? 128 * 40 : 8];
    const int tid = threadIdx.x, lane = tid & 63, w = tid >> 6;
    const int wr = (w >> 1) * 64, wc = (w & 1) * 64;
    const int ml = lane & 15, q8 = (lane >> 4) * 8, q4 = (lane >> 4) * 4;
    const int row0 = blockIdx.x * 128, col0 = blockIdx.y * 128;
    const int sm = tid >> 2, sk = (tid & 3) * 8;

    f32x4 acc[4][4];
#pragma unroll
    for (int i = 0; i < 4; ++i)
#pragma unroll
        for (int j = 0; j < 4; ++j) acc[i][j] = {0.f, 0.f, 0.f, 0.f};

    for (int k0 = 0; k0 < DM; k0 += 32) {
#pragma unroll
        for (int p = 0; p < 2; ++p) {
            int m = sm + p * 64;
            *(uint4*)&Ah[m * 40 + sk] = *(const uint4*)&Ah_g[(size_t)(row0 + m) * DM + k0 + sk];
            *(uint4*)&Bh[m * 40 + sk] = *(const uint4*)&Bh_g[(size_t)(col0 + m) * DM + k0 + sk];
            if (SPLIT) {
                *(uint4*)&Al[m * 40 + sk] = *(const uint4*)&Al_g[(size_t)(row0 + m) * DM + k0 + sk];
                *(uint4*)&Bl[m * 40 + sk] = *(const uint4*)&Bl_g[(size_t)(col0 + m) * DM + k0 + sk];
            }
        }
        __syncthreads();
        bf16x8 a_h[4], b_h[4], a_l[4], b_l[4];
#pragma unroll
        for (int i = 0; i < 4; ++i) {
            a_h[i] = *(const bf16x8*)&Ah[(wr + i * 16 + ml) * 40 + q8];
            b_h[i] = *(const bf16x8*)&Bh[(wc + i * 16 + ml) * 40 + q8];
            if (SPLIT) {
                a_l[i] = *(const bf16x8*)&Al[(wr + i * 16 + ml) * 40 + q8];
                b_l[i] = *(const bf16x8*)&Bl[(wc + i * 16 + ml) * 40 + q8];
            }
        }
#pragma unroll
        for (int i = 0; i < 4; ++i)
#pragma unroll
            for (int j = 0; j < 4; ++j) {
                acc[i][j] = MFMA_B16(a_h[i], b_h[j], acc[i][j]);
                if (SPLIT) {
                    acc[i][j] = MFMA_B16(a_h[i], b_l[j], acc[i][j]);
                    acc[i][j] = MFMA_B16(a_l[i], b_h[j], acc[i][j]);
                    acc[i][j] = MFMA_B16(a_l[i], b_l[j], acc[i][j]);
                }
            }
        __syncthreads();
    }

    float bcol[4];
#pragma unroll
    for (int j = 0; j < 4; ++j) bcol[j] = bias[col0 + wc + j * 16 + ml];
#pragma unroll
    for (int i = 0; i < 4; ++i)
#pragma unroll
        for (int j = 0; j < 4; ++j)
#pragma unroll
            for (int r = 0; r < 4; ++r) {
                int gm = row0 + wr + i * 16 + q4 + r;
                int gn = col0 + wc + j * 16 + ml;
                float t = acc[i][j][r] + bcol[j];
                if (RELU) t = fmaxf(t, 0.f);
                t *= scale;
                size_t off = (size_t)gm * DM + gn;
                if (OUTMODE == 0) {
                    if (R) t += R[off];
                    outF[off] = t;
                } else if (OUTMODE == 1) {
                    unsigned hb2 = f2b(t);
                    outHi[off] = (u16)hb2;
                    outLo[off] = (u16)f2b(t - b2f(hb2));
                } else {
                    outHi[off] = (u16)f2b(t);
                }
            }
}

// ---------------------------------------------------------------------------
// FUSED attention middle, v2: scores live in REGISTERS (16 f32x4/wave).
// Block = 16 query rows x one hb; wave w owns cols [w*256, w*256+256).
// Selection: all 16 rows bisected simultaneously; per-iteration cross-wave
// count combine via 256 B LDS. Chebyshev bracket guarantees exactness.
// ---------------------------------------------------------------------------
__global__ __launch_bounds__(256, 3) void attn_fused(
    const u16* __restrict__ qhi, const u16* __restrict__ qlo,
    const u16* __restrict__ khi, const u16* __restrict__ klo,
    const u16* __restrict__ vhi, u16* __restrict__ ao)
{
    __shared__ u16 Qh[16 * QSTR], Ql[16 * QSTR];
    __shared__ float statS[4][16], statQ[4][16];
    __shared__ int   cntW[4][16];
    __shared__ float pval[16][PCAP];
    __shared__ int   pcol[16][PCAP];
    __shared__ unsigned loU[16];

    const int tid = threadIdx.x, lane = tid & 63, w = tid >> 6;
    const int ml = lane & 15, quad = lane >> 4, q8 = quad * 8;
    const int hb = blockIdx.y, h = hb >> 3, b = hb & 7;
    const int r0 = blockIdx.x * 16;

    // ---- stage Q (16 rows x 64 dims, hi+lo planes) ----
    {
        int t2 = tid & 127, m = t2 >> 3, k8 = (t2 & 7) * 8;
        const u16* sp = (tid < 128) ? qhi : qlo;
        u16* dst = (tid < 128) ? Qh : Ql;
        *(uint4*)&dst[m * QSTR + k8] =
            *(const uint4*)&sp[((size_t)(b * NSQ + r0 + m)) * DM + h * HDIM + k8];
    }
    __syncthreads();

    bf16x8 a_h0 = *(const bf16x8*)&Qh[ml * QSTR + q8];
    bf16x8 a_h1 = *(const bf16x8*)&Qh[ml * QSTR + 32 + q8];
    bf16x8 a_l0 = *(const bf16x8*)&Ql[ml * QSTR + q8];
    bf16x8 a_l1 = *(const bf16x8*)&Ql[ml * QSTR + 32 + q8];

    // ---- phase 1: scores into registers ----
    const u16* khp = khi + ((size_t)(b * NSQ + w * 256 + ml)) * DM + h * HDIM + q8;
    const u16* klp = klo + ((size_t)(b * NSQ + w * 256 + ml)) * DM + h * HDIM + q8;

    f32x4 acc[16];
#pragma unroll
    for (int t = 0; t < 16; ++t) {
        bf16x8 bh0 = *(const bf16x8*)(khp);
        bf16x8 bh1 = *(const bf16x8*)(khp + 32);
        bf16x8 bl0 = *(const bf16x8*)(klp);
        bf16x8 bl1 = *(const bf16x8*)(klp + 32);
        f32x4 a0 = {0.f, 0.f, 0.f, 0.f}, a1 = {0.f, 0.f, 0.f, 0.f};
        a0 = MFMA_B16(a_h0, bh0, a0);
        a0 = MFMA_B16(a_h1, bh1, a0);
        a0 = MFMA_B16(a_l0, bh0, a0);
        a0 = MFMA_B16(a_l1, bh1, a0);
        a1 = MFMA_B16(a_h0, bl0, a1);
        a1 = MFMA_B16(a_h1, bl1, a1);
        a1 = MFMA_B16(a_l0, bl0, a1);
        a1 = MFMA_B16(a_l1, bl1, a1);
        acc[t] = a0 + a1;
        khp += 16 * DM;
        klp += 16 * DM;
    }
    // acc[t][r] = S[row = r0 + quad*4 + r][col = w*256 + t*16 + ml]

    // ---- stats: mu/sigma per row ----
    float s1[4] = {0.f, 0.f, 0.f, 0.f}, s2[4] = {0.f, 0.f, 0.f, 0.f};
#pragma unroll
    for (int t = 0; t < 16; ++t)
#pragma unroll
        for (int r = 0; r < 4; ++r) {
            float v = acc[t][r];
            s1[r] += v;
            s2[r] = fmaf(v, v, s2[r]);
        }
#pragma unroll
    for (int off = 8; off; off >>= 1)
#pragma unroll
        for (int r = 0; r < 4; ++r) {
            s1[r] += __shfl_xor(s1[r], off);
            s2[r] += __shfl_xor(s2[r], off);
        }
    if (ml == 0)
#pragma unroll
        for (int r = 0; r < 4; ++r) {
            statS[w][quad * 4 + r] = s1[r];
            statQ[w][quad * 4 + r] = s2[r];
        }
    __syncthreads();

    float mu[4], sg[4], lo_f[4], hi_f[4];
    unsigned lo_u[4], hi_u[4];
    int clo[4], chi[4];
#pragma unroll
    for (int r = 0; r < 4; ++r) {
        int row = quad * 4 + r;
        float S = statS[0][row] + statS[1][row] + statS[2][row] + statS[3][row];
        float Q = statQ[0][row] + statQ[1][row] + statQ[2][row] + statQ[3][row];
        mu[r] = S * (1.f / 1024.f);
        sg[r] = sqrtf(fmaxf(Q * (1.f / 1024.f) - mu[r] * mu[r], 0.f)) + 1e-20f;
        // Chebyshev: #{x <= mu-8s} <= 1024/64 = 16 < 32  ->  count(>lo) >= 32 guaranteed
        lo_f[r] = mu[r] - 8.f * sg[r];
        hi_f[r] = mu[r] + 8.f * sg[r];
        lo_u[r] = ordu(lo_f[r]);
        hi_u[r] = ordu(hi_f[r]);
        clo[r] = 1024;
        chi[r] = 0;
    }

    // ---- lockstep bisection for all 16 rows ----
    int done = 0;
    for (int iter = 0; iter < 40; ++iter) {
        float mid_f[4]; unsigned mid_u[4];
#pragma unroll
        for (int r = 0; r < 4; ++r) {
            if (!((done >> r) & 1)) {
                float fr; unsigned um;
                if (iter == 0)      fr = mu[r] + 2.02f * sg[r];
                else if (iter == 1) fr = mu[r] + 1.62f * sg[r];
                else if (iter & 1) {
                    um = lo_u[r] + ((hi_u[r] - lo_u[r]) >> 1);
                    fr = iordu(um); mid_u[r] = um; mid_f[r] = fr;
                    continue;
                } else {
                    float fc = (float)(clo[r] - TOPK) / (float)(clo[r] - chi[r]);
                    fc = fminf(fmaxf(fc, 0.04f), 0.96f);
                    fr = lo_f[r] + (hi_f[r] - lo_f[r]) * fc;
                }
                um = ordu(fr);
                if (um <= lo_u[r] || um >= hi_u[r]) {
                    um = lo_u[r] + ((hi_u[r] - lo_u[r]) >> 1);
                    fr = iordu(um);
                }
                mid_u[r] = um; mid_f[r] = fr;
            } else { mid_u[r] = lo_u[r]; mid_f[r] = lo_f[r]; }
        }
        int c[4] = {0, 0, 0, 0};
#pragma unroll
        for (int t = 0; t < 16; ++t)
#pragma unroll
            for (int r = 0; r < 4; ++r) c[r] += (acc[t][r] > mid_f[r]) ? 1 : 0;
#pragma unroll
        for (int off = 8; off; off >>= 1)
#pragma unroll
            for (int r = 0; r < 4; ++r) c[r] += __shfl_xor(c[r], off);
        if (ml == 0)
#pragma unroll
            for (int r = 0; r < 4; ++r) cntW[w][quad * 4 + r] = c[r];
        __syncthreads();
        int tot[4];
#pragma unroll
        for (int r = 0; r < 4; ++r) {
            int row = quad * 4 + r;
            tot[r] = cntW[0][row] + cntW[1][row] + cntW[2][row] + cntW[3][row];
        }
        __syncthreads();
#pragma unroll
        for (int r = 0; r < 4; ++r) {
            if (!((done >> r) & 1)) {
                if (tot[r] >= TOPK) {
                    lo_u[r] = mid_u[r]; lo_f[r] = mid_f[r]; clo[r] = tot[r];
                    if (tot[r] == TOPK) done |= 1 << r;
                } else {
                    hi_u[r] = mid_u[r]; hi_f[r] = mid_f[r]; chi[r] = tot[r];
                }
                if (hi_u[r] - lo_u[r] <= 1u) done |= 1 << r;
            }
        }
        if (__all(done == 15)) break;
    }

    // ---- final per-wave counts at lo (for prefix offsets + totals) ----
    {
        int c[4] = {0, 0, 0, 0};
#pragma unroll
        for (int t = 0; t < 16; ++t)
#pragma unroll
            for (int r = 0; r < 4; ++r) c[r] += (acc[t][r] > lo_f[r]) ? 1 : 0;
#pragma unroll
        for (int off = 8; off; off >>= 1)
#pragma unroll
            for (int r = 0; r < 4; ++r) c[r] += __shfl_xor(c[r], off);
        if (ml == 0)
#pragma unroll
            for (int r = 0; r < 4; ++r) cntW[w][quad * 4 + r] = c[r];
        if (w == 0 && ml == 0)
#pragma unroll
            for (int r = 0; r < 4; ++r) loU[quad * 4 + r] = lo_u[r];
    }
    __syncthreads();

    int base[4];
#pragma unroll
    for (int r = 0; r < 4; ++r) {
        int row = quad * 4 + r, s = 0;
#pragma unroll
        for (int ww = 0; ww < 4; ++ww) s += (ww < w) ? cntW[ww][row] : 0;
        base[r] = s;
    }

    // ---- extraction: ballot-prefix compaction into (val,col) pair buffers ----
    const unsigned lmask = (1u << ml) - 1u;
#pragma unroll
    for (int t = 0; t < 16; ++t)
#pragma unroll
        for (int r = 0; r < 4; ++r) {
            bool sel = acc[t][r] > lo_f[r];
            unsigned long long bm = __ballot(sel);
            unsigned mq = (unsigned)(bm >> (quad * 16)) & 0xFFFFu;
            if (sel) {
                int slot = base[r] + __popc(mq & lmask);
                if (slot < PCAP) {
                    pval[quad * 4 + r][slot] = acc[t][r];
                    pcol[quad * 4 + r][slot] = w * 256 + t * 16 + ml;
                }
            }
            base[r] += __popc(mq);
        }
    __syncthreads();

    // ---- finale: tie-prune (rare) + softmax + PV; wave w owns rows w*4..w*4+3
    const u16* vb = vhi + ((size_t)b * NSQ) * DM + h * HDIM + lane;
    for (int rr = 0; rr < 4; ++rr) {
        const int row = w * 4 + rr;
        int n = cntW[0][row] + cntW[1][row] + cntW[2][row] + cntW[3][row];
        if (n > PCAP) n = PCAP;
        float val = (lane < n) ? pval[row][lane] : -INFINITY;
        int   col = (lane < n) ? pcol[row][lane] : -1;
        int excess = n - TOPK;
        if (excess > 0) {
            float bf = iordu(loU[row] + 1u);   // boundary (tied) value
            while (excess > 0) {
                int cmx = (val == bf) ? col : -1;
#pragma unroll
                for (int off = 32; off; off >>= 1) cmx = max(cmx, __shfl_xor(cmx, off));
                if (cmx >= 0 && col == cmx && val == bf) val = -INFINITY;
                excess--;
            }
        }
        float m = val;
#pragma unroll
        for (int off = 32; off; off >>= 1) m = fmaxf(m, __shfl_xor(m, off));
        float e = (lane < n) ? __expf(val - m) : 0.f;
        float s = e;
#pragma unroll
        for (int off = 32; off; off >>= 1) s += __shfl_xor(s, off);
        if (lane < n) pval[row][lane] = e * (1.f / s);

        float accv = 0.f;
        for (int t = 0; t < n; ++t)
            accv = fmaf(pval[row][t], b2f(vb[(size_t)pcol[row][t] * DM]), accv);
        ao[((size_t)(b * NSQ + r0 + row)) * DM + h * HDIM + lane] = (u16)f2b(accv);
    }
}

// ---------------------------------------------------------------------------
// LayerNorm: out = LN(a [+ bf16 addb]) * g + be; optional fp32 + bf16-hi outs
// ---------------------------------------------------------------------------
__global__ __launch_bounds__(256) void ln_fused(
    const float* __restrict__ a, const u16* __restrict__ addb,
    const float* __restrict__ g, const float* __restrict__ be,
    float* __restrict__ outF, u16* __restrict__ outHi)
{
    __shared__ float red[4][2];
    const int row = blockIdx.x, tid = threadIdx.x, w = tid >> 6;
    float2 v = ((const float2*)(a + (size_t)row * DM))[tid];
    if (addb) {
        ushort2 ab = ((const ushort2*)(addb + (size_t)row * DM))[tid];
        v.x += b2f(ab.x); v.y += b2f(ab.y);
    }
    float s = v.x + v.y, q = v.x * v.x + v.y * v.y;
#pragma unroll
    for (int o = 32; o; o >>= 1) { s += __shfl_xor(s, o); q += __shfl_xor(q, o); }
    if ((tid & 63) == 0) { red[w][0] = s; red[w][1] = q; }
    __syncthreads();
    float S = red[0][0] + red[1][0] + red[2][0] + red[3][0];
    float Q = red[0][1] + red[1][1] + red[2][1] + red[3][1];
    float mu = S * (1.f / DM);
    float var = Q * (1.f / DM) - mu * mu;
    float rs = rsqrtf(var + 1e-5f);
    float2 gv = ((const float2*)g)[tid];
    float2 bv = ((const float2*)be)[tid];
    float2 o;
    o.x = (v.x - mu) * rs * gv.x + bv.x;
    o.y = (v.y - mu) * rs * gv.y + bv.y;
    if (outF) ((float2*)(outF + (size_t)row * DM))[tid] = o;
    if (outHi) {
        ushort2 hv; hv.x = (u16)f2b(o.x); hv.y = (u16)f2b(o.y);
        ((ushort2*)(outHi + (size_t)row * DM))[tid] = hv;
    }
}

// ---------------------------------------------------------------------------
extern "C" void kernel_launch(void* const* d_in, const int* in_sizes, int n_in,
                              void* d_out, int out_size, void* d_ws, size_t ws_size,
                              hipStream_t stream) {
    const float* src = (const float*)d_in[0];
    const float* tgt = (const float*)d_in[1];
    const float* Wq  = (const float*)d_in[2];
    const float* bq  = (const float*)d_in[3];
    const float* Wk  = (const float*)d_in[4];
    const float* bk  = (const float*)d_in[5];
    const float* Wv  = (const float*)d_in[6];
    const float* bv  = (const float*)d_in[7];
    const float* W1  = (const float*)d_in[8];
    const float* b1  = (const float*)d_in[9];
    const float* W2  = (const float*)d_in[10];
    const float* b2  = (const float*)d_in[11];
    const float* g1  = (const float*)d_in[12];
    const float* be1 = (const float*)d_in[13];
    const float* g2  = (const float*)d_in[14];
    const float* be2 = (const float*)d_in[15];

    // workspace map (MB offsets). Total footprint: 136 MB.
    const size_t WPLANE = (size_t)DM * DM;
    u16* planes = (u16*)d_ws;                    // 10 x 512 KB = 5 MB
    auto wh = [&](int i) { return planes + (size_t)i * 2 * WPLANE; };
    auto wl = [&](int i) { return planes + (size_t)i * 2 * WPLANE + WPLANE; };
    auto at = [&](size_t mb) { return (char*)d_ws + (mb << 20); };
    u16* Thi = (u16*)at(8);   u16* Tlo = (u16*)at(16);
    u16* Shi = (u16*)at(24);  u16* Slo = (u16*)at(32);
    u16* qhi = (u16*)at(40);  u16* qlo = (u16*)at(48);
    u16* khi = (u16*)at(56);  u16* klo = (u16*)at(64);
    u16* vhi = (u16*)at(72);
    u16* aob = (u16*)at(80);
    float* xb = (float*)at(88);                  // 16 MB fp32
    u16* xhi = (u16*)at(104);
    u16* hhi = (u16*)at(112);
    float* f2 = (float*)at(120);                 // 16 MB fp32

    dim3 blk(256);
    const float qscale = 0.04419417382415922f;   // 1/sqrt(512)

    wconv5<<<dim3(16, 16, 5), blk, 0, stream>>>(Wq, Wk, Wv, W1, W2, planes);
    conv2<<<dim3(4096, 2), blk, 0, stream>>>(tgt, src, Thi, Tlo, Shi, Slo);

    mm512<1, 0, 1><<<dim3(64, 4), blk, 0, stream>>>(Thi, Tlo, wh(0), wl(0), bq, nullptr,
                                                    qscale, nullptr, qhi, qlo);
    mm512<1, 0, 1><<<dim3(64, 4), blk, 0, stream>>>(Shi, Slo, wh(1), wl(1), bk, nullptr,
                                                    1.f, nullptr, khi, klo);
    mm512<0, 0, 2><<<dim3(64, 4), blk, 0, stream>>>(Shi, nullptr, wh(2), nullptr, bv, nullptr,
                                                    1.f, nullptr, vhi, nullptr);

    attn_fused<<<dim3(64, 64), blk, 0, stream>>>(qhi, qlo, khi, klo, vhi, aob);

    ln_fused<<<8192, blk, 0, stream>>>(tgt, aob, g1, be1, xb, xhi);
    mm512<0, 1, 2><<<dim3(64, 4), blk, 0, stream>>>(xhi, nullptr, wh(3), nullptr, b1, nullptr,
                                                    1.f, nullptr, hhi, nullptr);
    mm512<0, 0, 0><<<dim3(64, 4), blk, 0, stream>>>(hhi, nullptr, wh(4), nullptr, b2, xb,
                                                    1.f, f2, nullptr, nullptr);
    ln_fused<<<8192, blk, 0, stream>>>(f2, nullptr, g2, be2, (float*)d_out, nullptr);
}

// Round 6
// 435.351 us; speedup vs baseline: 1.2546x; 1.2110x over previous
//
#include <hip/hip_runtime.h>
#include <math.h>

#define NSQ 1024
#define DM  512
#define HDIM 64
#define TOPK 32
#define QSTR 72   // LDS stride for staged Q (16B-aligned, conflict-free frags)
#define PCAP 64   // candidate buffer capacity per row (one per lane)

typedef unsigned short u16;
typedef __attribute__((ext_vector_type(8))) short bf16x8;
typedef __attribute__((ext_vector_type(4))) float f32x4;

#define MFMA_B16(A,B,C) __builtin_amdgcn_mfma_f32_16x16x32_bf16(A,B,C,0,0,0)

__device__ __forceinline__ unsigned f2b(float x) {
    unsigned u = __float_as_uint(x);
    return (u + 0x7FFFu + ((u >> 16) & 1u)) >> 16;   // RN-even to bf16 bits
}
__device__ __forceinline__ float b2f(unsigned h) { return __uint_as_float(h << 16); }
__device__ __forceinline__ unsigned ordu(float f) {
    unsigned b = __float_as_uint(f);
    return b ^ (0x80000000u | (unsigned)((int)b >> 31));  // order-preserving uint
}
__device__ __forceinline__ float iordu(unsigned u) {
    unsigned b = (u & 0x80000000u) ? (u ^ 0x80000000u) : ~u;
    return __uint_as_float(b);
}

// ---------------------------------------------------------------------------
// fp32 [8192x512] x2 -> bf16 hi/lo planes (tgt -> T*, src -> S*)
// ---------------------------------------------------------------------------
__global__ __launch_bounds__(256) void conv2(
    const float* __restrict__ tgt, const float* __restrict__ src,
    u16* __restrict__ Thi, u16* __restrict__ Tlo,
    u16* __restrict__ Shi, u16* __restrict__ Slo)
{
    const int z = blockIdx.y;
    const float* x = z ? src : tgt;
    u16* hi = z ? Shi : Thi;
    u16* lo = z ? Slo : Tlo;
    int idx = blockIdx.x * 256 + threadIdx.x;
    float4 v = ((const float4*)x)[idx];
    float f[4] = {v.x, v.y, v.z, v.w};
    ushort4 hv, lv;
    unsigned h;
    h = f2b(f[0]); hv.x = (u16)h; lv.x = (u16)f2b(f[0] - b2f(h));
    h = f2b(f[1]); hv.y = (u16)h; lv.y = (u16)f2b(f[1] - b2f(h));
    h = f2b(f[2]); hv.z = (u16)h; lv.z = (u16)f2b(f[2] - b2f(h));
    h = f2b(f[3]); hv.w = (u16)h; lv.w = (u16)f2b(f[3] - b2f(h));
    ((ushort4*)hi)[idx] = hv;
    ((ushort4*)lo)[idx] = lv;
}

// ---------------------------------------------------------------------------
// All 5 weights [512,512] -> transposed bf16 hi/lo planes, one dispatch.
// ---------------------------------------------------------------------------
__global__ __launch_bounds__(256) void wconv5(
    const float* __restrict__ Wq, const float* __restrict__ Wk,
    const float* __restrict__ Wv, const float* __restrict__ W1,
    const float* __restrict__ W2, u16* __restrict__ planes)
{
    __shared__ float T[32][33];
    const int wsel = blockIdx.z;
    const float* W = (wsel == 0) ? Wq : (wsel == 1) ? Wk : (wsel == 2) ? Wv
                   : (wsel == 3) ? W1 : W2;
    u16* thi = planes + (size_t)wsel * 2 * DM * DM;
    u16* tlo = thi + (size_t)DM * DM;
    const int tx = threadIdx.x & 31, ty = threadIdx.x >> 5;
    const int n0 = blockIdx.x * 32, k0 = blockIdx.y * 32;
#pragma unroll
    for (int p = 0; p < 4; ++p) {
        int r = ty + p * 8;
        T[r][tx] = W[(size_t)(k0 + r) * DM + n0 + tx];
    }
    __syncthreads();
#pragma unroll
    for (int p = 0; p < 4; ++p) {
        int rr = ty + p * 8;
        float val = T[tx][rr];                       // = W[k0+tx][n0+rr]
        unsigned h = f2b(val);
        size_t off = (size_t)(n0 + rr) * DM + k0 + tx;
        thi[off] = (u16)h;
        tlo[off] = (u16)f2b(val - b2f(h));
    }
}

// ---------------------------------------------------------------------------
// C[8192,512] = act((Ahi+Alo) @ (Bhi+Blo)^T + bias)*scale (+R)
// 128x128 tile, 4 waves x (4x4 of 16x16x32 MFMA), BK=32.
// OUTMODE: 0 = fp32 (+R), 1 = bf16 hi+lo planes, 2 = bf16 hi only.
// ---------------------------------------------------------------------------
template<int SPLIT, int RELU, int OUTMODE>
__global__ __launch_bounds__(256) void mm512(
    const u16* __restrict__ Ah_g, const u16* __restrict__ Al_g,
    const u16* __restrict__ Bh_g, const u16* __restrict__ Bl_g,
    const float* __restrict__ bias, const float* __restrict__ R,
    float scale, float* __restrict__ outF,
    u16* __restrict__ outHi, u16* __restrict__ outLo)
{
    __shared__ u16 Ah[128 * 40], Bh[128 * 40];
    __shared__ u16 Al[SPLIT ? 128 * 40 : 8], Bl[SPLIT ? 128 * 40 : 8];
    const int tid = threadIdx.x, lane = tid & 63, w = tid >> 6;
    const int wr = (w >> 1) * 64, wc = (w & 1) * 64;
    const int ml = lane & 15, q8 = (lane >> 4) * 8, q4 = (lane >> 4) * 4;
    const int row0 = blockIdx.x * 128, col0 = blockIdx.y * 128;
    const int sm = tid >> 2, sk = (tid & 3) * 8;

    f32x4 acc[4][4];
#pragma unroll
    for (int i = 0; i < 4; ++i)
#pragma unroll
        for (int j = 0; j < 4; ++j) acc[i][j] = {0.f, 0.f, 0.f, 0.f};

    for (int k0 = 0; k0 < DM; k0 += 32) {
#pragma unroll
        for (int p = 0; p < 2; ++p) {
            int m = sm + p * 64;
            *(uint4*)&Ah[m * 40 + sk] = *(const uint4*)&Ah_g[(size_t)(row0 + m) * DM + k0 + sk];
            *(uint4*)&Bh[m * 40 + sk] = *(const uint4*)&Bh_g[(size_t)(col0 + m) * DM + k0 + sk];
            if (SPLIT) {
                *(uint4*)&Al[m * 40 + sk] = *(const uint4*)&Al_g[(size_t)(row0 + m) * DM + k0 + sk];
                *(uint4*)&Bl[m * 40 + sk] = *(const uint4*)&Bl_g[(size_t)(col0 + m) * DM + k0 + sk];
            }
        }
        __syncthreads();
        bf16x8 a_h[4], b_h[4], a_l[4], b_l[4];
#pragma unroll
        for (int i = 0; i < 4; ++i) {
            a_h[i] = *(const bf16x8*)&Ah[(wr + i * 16 + ml) * 40 + q8];
            b_h[i] = *(const bf16x8*)&Bh[(wc + i * 16 + ml) * 40 + q8];
            if (SPLIT) {
                a_l[i] = *(const bf16x8*)&Al[(wr + i * 16 + ml) * 40 + q8];
                b_l[i] = *(const bf16x8*)&Bl[(wc + i * 16 + ml) * 40 + q8];
            }
        }
#pragma unroll
        for (int i = 0; i < 4; ++i)
#pragma unroll
            for (int j = 0; j < 4; ++j) {
                acc[i][j] = MFMA_B16(a_h[i], b_h[j], acc[i][j]);
                if (SPLIT) {
                    acc[i][j] = MFMA_B16(a_h[i], b_l[j], acc[i][j]);
                    acc[i][j] = MFMA_B16(a_l[i], b_h[j], acc[i][j]);
                    acc[i][j] = MFMA_B16(a_l[i], b_l[j], acc[i][j]);
                }
            }
        __syncthreads();
    }

    float bcol[4];
#pragma unroll
    for (int j = 0; j < 4; ++j) bcol[j] = bias[col0 + wc + j * 16 + ml];
#pragma unroll
    for (int i = 0; i < 4; ++i)
#pragma unroll
        for (int j = 0; j < 4; ++j)
#pragma unroll
            for (int r = 0; r < 4; ++r) {
                int gm = row0 + wr + i * 16 + q4 + r;
                int gn = col0 + wc + j * 16 + ml;
                float t = acc[i][j][r] + bcol[j];
                if (RELU) t = fmaxf(t, 0.f);
                t *= scale;
                size_t off = (size_t)gm * DM + gn;
                if (OUTMODE == 0) {
                    if (R) t += R[off];
                    outF[off] = t;
                } else if (OUTMODE == 1) {
                    unsigned hb2 = f2b(t);
                    outHi[off] = (u16)hb2;
                    outLo[off] = (u16)f2b(t - b2f(hb2));
                } else {
                    outHi[off] = (u16)f2b(t);
                }
            }
}

// ---------------------------------------------------------------------------
// FUSED attention middle, v3: scores in registers; CROSS-WAVE phase only
// brackets count into [TOPK, 64] (1-2 probes, few barriers); exact top-32
// resolved per-wave by a ballot micro-bisect over <=64 lane-resident
// candidates; PV gather with 8-wide load batching.
// ---------------------------------------------------------------------------
__global__ __launch_bounds__(256, 4) void attn_fused(
    const u16* __restrict__ qhi, const u16* __restrict__ qlo,
    const u16* __restrict__ khi, const u16* __restrict__ klo,
    const u16* __restrict__ vhi, u16* __restrict__ ao)
{
    __shared__ u16 Qh[16 * QSTR], Ql[16 * QSTR];
    __shared__ float statS[4][16], statQ[4][16];
    __shared__ int   cntW[4][16];
    __shared__ float pval[16][PCAP];
    __shared__ int   pcol[16][PCAP];
    __shared__ unsigned loU[16];

    const int tid = threadIdx.x, lane = tid & 63, w = tid >> 6;
    const int ml = lane & 15, quad = lane >> 4, q8 = quad * 8;
    const int hb = blockIdx.y, h = hb >> 3, b = hb & 7;
    const int r0 = blockIdx.x * 16;

    // ---- stage Q (16 rows x 64 dims, hi+lo planes) ----
    {
        int t2 = tid & 127, m = t2 >> 3, k8 = (t2 & 7) * 8;
        const u16* sp = (tid < 128) ? qhi : qlo;
        u16* dst = (tid < 128) ? Qh : Ql;
        *(uint4*)&dst[m * QSTR + k8] =
            *(const uint4*)&sp[((size_t)(b * NSQ + r0 + m)) * DM + h * HDIM + k8];
    }
    __syncthreads();

    bf16x8 a_h0 = *(const bf16x8*)&Qh[ml * QSTR + q8];
    bf16x8 a_h1 = *(const bf16x8*)&Qh[ml * QSTR + 32 + q8];
    bf16x8 a_l0 = *(const bf16x8*)&Ql[ml * QSTR + q8];
    bf16x8 a_l1 = *(const bf16x8*)&Ql[ml * QSTR + 32 + q8];

    // ---- phase 1: scores into registers ----
    const u16* khp = khi + ((size_t)(b * NSQ + w * 256 + ml)) * DM + h * HDIM + q8;
    const u16* klp = klo + ((size_t)(b * NSQ + w * 256 + ml)) * DM + h * HDIM + q8;

    f32x4 acc[16];
#pragma unroll
    for (int t = 0; t < 16; ++t) {
        bf16x8 bh0 = *(const bf16x8*)(khp);
        bf16x8 bh1 = *(const bf16x8*)(khp + 32);
        bf16x8 bl0 = *(const bf16x8*)(klp);
        bf16x8 bl1 = *(const bf16x8*)(klp + 32);
        f32x4 a0 = {0.f, 0.f, 0.f, 0.f}, a1 = {0.f, 0.f, 0.f, 0.f};
        a0 = MFMA_B16(a_h0, bh0, a0);
        a0 = MFMA_B16(a_h1, bh1, a0);
        a0 = MFMA_B16(a_l0, bh0, a0);
        a0 = MFMA_B16(a_l1, bh1, a0);
        a1 = MFMA_B16(a_h0, bl0, a1);
        a1 = MFMA_B16(a_h1, bl1, a1);
        a1 = MFMA_B16(a_l0, bl0, a1);
        a1 = MFMA_B16(a_l1, bl1, a1);
        acc[t] = a0 + a1;
        khp += 16 * DM;
        klp += 16 * DM;
    }
    // acc[t][r] = S[row = quad*4 + r][col = w*256 + t*16 + ml]

    // ---- stats: mu/sigma per row ----
    float s1[4] = {0.f, 0.f, 0.f, 0.f}, s2[4] = {0.f, 0.f, 0.f, 0.f};
#pragma unroll
    for (int t = 0; t < 16; ++t)
#pragma unroll
        for (int r = 0; r < 4; ++r) {
            float v = acc[t][r];
            s1[r] += v;
            s2[r] = fmaf(v, v, s2[r]);
        }
#pragma unroll
    for (int off = 8; off; off >>= 1)
#pragma unroll
        for (int r = 0; r < 4; ++r) {
            s1[r] += __shfl_xor(s1[r], off);
            s2[r] += __shfl_xor(s2[r], off);
        }
    if (ml == 0)
#pragma unroll
        for (int r = 0; r < 4; ++r) {
            statS[w][quad * 4 + r] = s1[r];
            statQ[w][quad * 4 + r] = s2[r];
        }
    __syncthreads();

    float mu[4], sg[4], lo_f[4], hi_f[4];
    unsigned lo_u[4], hi_u[4];
    int clo[4];
#pragma unroll
    for (int r = 0; r < 4; ++r) {
        int row = quad * 4 + r;
        float S = statS[0][row] + statS[1][row] + statS[2][row] + statS[3][row];
        float Q = statQ[0][row] + statQ[1][row] + statQ[2][row] + statQ[3][row];
        mu[r] = S * (1.f / 1024.f);
        sg[r] = sqrtf(fmaxf(Q * (1.f / 1024.f) - mu[r] * mu[r], 0.f)) + 1e-20f;
        // Chebyshev: #{x <= mu-8s} <= 1024/64 = 16 < 32  ->  count(>lo) >= 32 guaranteed
        lo_f[r] = mu[r] - 8.f * sg[r];
        hi_f[r] = mu[r] + 8.f * sg[r];
        lo_u[r] = ordu(lo_f[r]);
        hi_u[r] = ordu(hi_f[r]);
        clo[r] = 1024;
    }

    // ---- lockstep WINDOW probe: bracket count into [TOPK, PCAP] ----
    int done = 0;
    for (int iter = 0; iter < 24; ++iter) {
        float mid_f[4]; unsigned mid_u[4];
#pragma unroll
        for (int r = 0; r < 4; ++r) {
            if (!((done >> r) & 1)) {
                float fr; unsigned um;
                if (iter == 0)      fr = mu[r] + 1.70f * sg[r];
                else if (iter == 1) fr = mu[r] + ((clo[r] == 1024) ? 1.38f : 2.15f) * sg[r];
                else {
                    um = lo_u[r] + ((hi_u[r] - lo_u[r]) >> 1);
                    fr = iordu(um); mid_u[r] = um; mid_f[r] = fr;
                    continue;
                }
                um = ordu(fr);
                if (um <= lo_u[r] || um >= hi_u[r]) {
                    um = lo_u[r] + ((hi_u[r] - lo_u[r]) >> 1);
                    fr = iordu(um);
                }
                mid_u[r] = um; mid_f[r] = fr;
            } else { mid_u[r] = lo_u[r]; mid_f[r] = lo_f[r]; }
        }
        int c[4] = {0, 0, 0, 0};
#pragma unroll
        for (int t = 0; t < 16; ++t)
#pragma unroll
            for (int r = 0; r < 4; ++r) c[r] += (acc[t][r] > mid_f[r]) ? 1 : 0;
#pragma unroll
        for (int off = 8; off; off >>= 1)
#pragma unroll
            for (int r = 0; r < 4; ++r) c[r] += __shfl_xor(c[r], off);
        if (ml == 0)
#pragma unroll
            for (int r = 0; r < 4; ++r) cntW[w][quad * 4 + r] = c[r];
        __syncthreads();
        int tot[4];
#pragma unroll
        for (int r = 0; r < 4; ++r) {
            int row = quad * 4 + r;
            tot[r] = cntW[0][row] + cntW[1][row] + cntW[2][row] + cntW[3][row];
        }
        __syncthreads();
#pragma unroll
        for (int r = 0; r < 4; ++r) {
            if (!((done >> r) & 1)) {
                if (tot[r] >= TOPK) {
                    lo_u[r] = mid_u[r]; lo_f[r] = mid_f[r]; clo[r] = tot[r];
                    if (tot[r] <= PCAP) done |= 1 << r;    // window hit
                } else {
                    hi_u[r] = mid_u[r]; hi_f[r] = mid_f[r];
                }
                if (hi_u[r] - lo_u[r] <= 1u) done |= 1 << r;
            }
        }
        if (__all(done == 15)) break;
    }

    // ---- final per-wave counts at lo (prefix offsets + totals) ----
    {
        int c[4] = {0, 0, 0, 0};
#pragma unroll
        for (int t = 0; t < 16; ++t)
#pragma unroll
            for (int r = 0; r < 4; ++r) c[r] += (acc[t][r] > lo_f[r]) ? 1 : 0;
#pragma unroll
        for (int off = 8; off; off >>= 1)
#pragma unroll
            for (int r = 0; r < 4; ++r) c[r] += __shfl_xor(c[r], off);
        if (ml == 0)
#pragma unroll
            for (int r = 0; r < 4; ++r) cntW[w][quad * 4 + r] = c[r];
        if (w == 0 && ml == 0)
#pragma unroll
            for (int r = 0; r < 4; ++r) loU[quad * 4 + r] = lo_u[r];
    }
    __syncthreads();

    int base[4];
#pragma unroll
    for (int r = 0; r < 4; ++r) {
        int row = quad * 4 + r, s = 0;
#pragma unroll
        for (int ww = 0; ww < 4; ++ww) s += (ww < w) ? cntW[ww][row] : 0;
        base[r] = s;
    }

    // ---- extraction: ballot-prefix compaction into (val,col) pair buffers ----
    const unsigned lmask = (1u << ml) - 1u;
#pragma unroll
    for (int t = 0; t < 16; ++t)
#pragma unroll
        for (int r = 0; r < 4; ++r) {
            bool sel = acc[t][r] > lo_f[r];
            unsigned long long bm = __ballot(sel);
            unsigned mq = (unsigned)(bm >> (quad * 16)) & 0xFFFFu;
            if (sel) {
                int slot = base[r] + __popc(mq & lmask);
                if (slot < PCAP) {
                    pval[quad * 4 + r][slot] = acc[t][r];
                    pcol[quad * 4 + r][slot] = w * 256 + t * 16 + ml;
                }
            }
            base[r] += __popc(mq);
        }
    __syncthreads();

    // ---- finale per wave (rows w*4..w*4+3): micro-bisect to exact 32,
    //      tie-prune, softmax, compact, batched PV.
    const u16* vb = vhi + ((size_t)b * NSQ) * DM + h * HDIM + lane;
    for (int rr = 0; rr < 4; ++rr) {
        const int row = w * 4 + rr;
        int n = cntW[0][row] + cntW[1][row] + cntW[2][row] + cntW[3][row];
        if (n > PCAP) n = PCAP;
        float val = (lane < n) ? pval[row][lane] : 0.f;
        int   col = (lane < n) ? pcol[row][lane] : 0;
        unsigned uv = (lane < n) ? ordu(val) : 0u;

        // micro-bisect over lane-resident candidates: count(>blo) >= 32 invariant
        unsigned blo = loU[row], bhi = 0xFFFFFFFFu;
        while (bhi - blo > 1u) {
            unsigned mid = blo + ((bhi - blo) >> 1);
            int c = __popcll(__ballot(uv > mid));
            if (c >= TOPK) { blo = mid; if (c == TOPK) break; }
            else bhi = mid;
        }
        bool sel = uv > blo;
        int excess = __popcll(__ballot(sel)) - TOPK;
        while (excess > 0) {        // ties at boundary value (rare): drop largest cols
            int mycol = (sel && uv == blo + 1u) ? col : -1;
            int cmx = mycol;
#pragma unroll
            for (int off = 32; off; off >>= 1) cmx = max(cmx, __shfl_xor(cmx, off));
            if (sel && mycol >= 0 && col == cmx) sel = false;
            excess--;
        }

        float vsel = sel ? val : -INFINITY;
        float m = vsel;
#pragma unroll
        for (int off = 32; off; off >>= 1) m = fmaxf(m, __shfl_xor(m, off));
        float e = sel ? __expf(val - m) : 0.f;
        float s = e;
#pragma unroll
        for (int off = 32; off; off >>= 1) s += __shfl_xor(s, off);
        float p = e * (1.f / s);

        // compact selected 32 to slots 0..31 (wave-local; lgkm orders wr->rd)
        unsigned long long bm = __ballot(sel);
        int slot = __popcll(bm & ((1ull << lane) - 1ull));
        if (sel) { pval[row][slot] = p; pcol[row][slot] = col; }

        float accv = 0.f;
#pragma unroll
        for (int t0 = 0; t0 < TOPK; t0 += 8) {
            float pp[8]; int cc[8]; u16 vv[8];
#pragma unroll
            for (int j = 0; j < 8; ++j) { pp[j] = pval[row][t0 + j]; cc[j] = pcol[row][t0 + j]; }
#pragma unroll
            for (int j = 0; j < 8; ++j) vv[j] = vb[(size_t)cc[j] * DM];
#pragma unroll
            for (int j = 0; j < 8; ++j) accv = fmaf(pp[j], b2f(vv[j]), accv);
        }
        ao[((size_t)(b * NSQ + r0 + row)) * DM + h * HDIM + lane] = (u16)f2b(accv);
    }
}

// ---------------------------------------------------------------------------
// LayerNorm: out = LN(a [+ bf16 addb]) * g + be; optional fp32 + bf16-hi outs
// ---------------------------------------------------------------------------
__global__ __launch_bounds__(256) void ln_fused(
    const float* __restrict__ a, const u16* __restrict__ addb,
    const float* __restrict__ g, const float* __restrict__ be,
    float* __restrict__ outF, u16* __restrict__ outHi)
{
    __shared__ float red[4][2];
    const int row = blockIdx.x, tid = threadIdx.x, w = tid >> 6;
    float2 v = ((const float2*)(a + (size_t)row * DM))[tid];
    if (addb) {
        ushort2 ab = ((const ushort2*)(addb + (size_t)row * DM))[tid];
        v.x += b2f(ab.x); v.y += b2f(ab.y);
    }
    float s = v.x + v.y, q = v.x * v.x + v.y * v.y;
#pragma unroll
    for (int o = 32; o; o >>= 1) { s += __shfl_xor(s, o); q += __shfl_xor(q, o); }
    if ((tid & 63) == 0) { red[w][0] = s; red[w][1] = q; }
    __syncthreads();
    float S = red[0][0] + red[1][0] + red[2][0] + red[3][0];
    float Q = red[0][1] + red[1][1] + red[2][1] + red[3][1];
    float mu = S * (1.f / DM);
    float var = Q * (1.f / DM) - mu * mu;
    float rs = rsqrtf(var + 1e-5f);
    float2 gv = ((const float2*)g)[tid];
    float2 bv = ((const float2*)be)[tid];
    float2 o;
    o.x = (v.x - mu) * rs * gv.x + bv.x;
    o.y = (v.y - mu) * rs * gv.y + bv.y;
    if (outF) ((float2*)(outF + (size_t)row * DM))[tid] = o;
    if (outHi) {
        ushort2 hv; hv.x = (u16)f2b(o.x); hv.y = (u16)f2b(o.y);
        ((ushort2*)(outHi + (size_t)row * DM))[tid] = hv;
    }
}

// ---------------------------------------------------------------------------
extern "C" void kernel_launch(void* const* d_in, const int* in_sizes, int n_in,
                              void* d_out, int out_size, void* d_ws, size_t ws_size,
                              hipStream_t stream) {
    const float* src = (const float*)d_in[0];
    const float* tgt = (const float*)d_in[1];
    const float* Wq  = (const float*)d_in[2];
    const float* bq  = (const float*)d_in[3];
    const float* Wk  = (const float*)d_in[4];
    const float* bk  = (const float*)d_in[5];
    const float* Wv  = (const float*)d_in[6];
    const float* bv  = (const float*)d_in[7];
    const float* W1  = (const float*)d_in[8];
    const float* b1  = (const float*)d_in[9];
    const float* W2  = (const float*)d_in[10];
    const float* b2  = (const float*)d_in[11];
    const float* g1  = (const float*)d_in[12];
    const float* be1 = (const float*)d_in[13];
    const float* g2  = (const float*)d_in[14];
    const float* be2 = (const float*)d_in[15];

    // workspace map (MB offsets). Total footprint: 136 MB.
    const size_t WPLANE = (size_t)DM * DM;
    u16* planes = (u16*)d_ws;                    // 10 x 512 KB = 5 MB
    auto wh = [&](int i) { return planes + (size_t)i * 2 * WPLANE; };
    auto wl = [&](int i) { return planes + (size_t)i * 2 * WPLANE + WPLANE; };
    auto at = [&](size_t mb) { return (char*)d_ws + (mb << 20); };
    u16* Thi = (u16*)at(8);   u16* Tlo = (u16*)at(16);
    u16* Shi = (u16*)at(24);  u16* Slo = (u16*)at(32);
    u16* qhi = (u16*)at(40);  u16* qlo = (u16*)at(48);
    u16* khi = (u16*)at(56);  u16* klo = (u16*)at(64);
    u16* vhi = (u16*)at(72);
    u16* aob = (u16*)at(80);
    float* xb = (float*)at(88);                  // 16 MB fp32
    u16* xhi = (u16*)at(104);
    u16* hhi = (u16*)at(112);
    float* f2 = (float*)at(120);                 // 16 MB fp32

    dim3 blk(256);
    const float qscale = 0.04419417382415922f;   // 1/sqrt(512)

    wconv5<<<dim3(16, 16, 5), blk, 0, stream>>>(Wq, Wk, Wv, W1, W2, planes);
    conv2<<<dim3(4096, 2), blk, 0, stream>>>(tgt, src, Thi, Tlo, Shi, Slo);

    mm512<1, 0, 1><<<dim3(64, 4), blk, 0, stream>>>(Thi, Tlo, wh(0), wl(0), bq, nullptr,
                                                    qscale, nullptr, qhi, qlo);
    mm512<1, 0, 1><<<dim3(64, 4), blk, 0, stream>>>(Shi, Slo, wh(1), wl(1), bk, nullptr,
                                                    1.f, nullptr, khi, klo);
    mm512<0, 0, 2><<<dim3(64, 4), blk, 0, stream>>>(Shi, nullptr, wh(2), nullptr, bv, nullptr,
                                                    1.f, nullptr, vhi, nullptr);

    attn_fused<<<dim3(64, 64), blk, 0, stream>>>(qhi, qlo, khi, klo, vhi, aob);

    ln_fused<<<8192, blk, 0, stream>>>(tgt, aob, g1, be1, xb, xhi);
    mm512<0, 1, 2><<<dim3(64, 4), blk, 0, stream>>>(xhi, nullptr, wh(3), nullptr, b1, nullptr,
                                                    1.f, nullptr, hhi, nullptr);
    mm512<0, 0, 0><<<dim3(64, 4), blk, 0, stream>>>(hhi, nullptr, wh(4), nullptr, b2, xb,
                                                    1.f, f2, nullptr, nullptr);
    ln_fused<<<8192, blk, 0, stream>>>(f2, nullptr, g2, be2, (float*)d_out, nullptr);
}

// Round 7
// 397.005 us; speedup vs baseline: 1.3758x; 1.0966x over previous
//
#include <hip/hip_runtime.h>
#include <math.h>

#define NSQ 1024
#define DM  512
#define HDIM 64
#define TOPK 32
#define QSTR 72   // LDS stride for staged Q (16B-aligned, conflict-free frags)
#define PCAP 64   // candidate buffer capacity per row (one per lane)

typedef unsigned short u16;
typedef __attribute__((ext_vector_type(8))) short bf16x8;
typedef __attribute__((ext_vector_type(4))) float f32x4;

#define MFMA_B16(A,B,C) __builtin_amdgcn_mfma_f32_16x16x32_bf16(A,B,C,0,0,0)

__device__ __forceinline__ unsigned f2b(float x) {
    unsigned u = __float_as_uint(x);
    return (u + 0x7FFFu + ((u >> 16) & 1u)) >> 16;   // RN-even to bf16 bits
}
__device__ __forceinline__ float b2f(unsigned h) { return __uint_as_float(h << 16); }
__device__ __forceinline__ unsigned ordu(float f) {
    unsigned b = __float_as_uint(f);
    return b ^ (0x80000000u | (unsigned)((int)b >> 31));  // order-preserving uint
}
__device__ __forceinline__ float iordu(unsigned u) {
    unsigned b = (u & 0x80000000u) ? (u ^ 0x80000000u) : ~u;
    return __uint_as_float(b);
}

// ---------------------------------------------------------------------------
// fp32 [8192x512] x2 -> bf16 hi/lo planes (tgt -> T*, src -> S*)
// ---------------------------------------------------------------------------
__global__ __launch_bounds__(256) void conv2(
    const float* __restrict__ tgt, const float* __restrict__ src,
    u16* __restrict__ Thi, u16* __restrict__ Tlo,
    u16* __restrict__ Shi, u16* __restrict__ Slo)
{
    const int z = blockIdx.y;
    const float* x = z ? src : tgt;
    u16* hi = z ? Shi : Thi;
    u16* lo = z ? Slo : Tlo;
    int idx = blockIdx.x * 256 + threadIdx.x;
    float4 v = ((const float4*)x)[idx];
    float f[4] = {v.x, v.y, v.z, v.w};
    ushort4 hv, lv;
    unsigned h;
    h = f2b(f[0]); hv.x = (u16)h; lv.x = (u16)f2b(f[0] - b2f(h));
    h = f2b(f[1]); hv.y = (u16)h; lv.y = (u16)f2b(f[1] - b2f(h));
    h = f2b(f[2]); hv.z = (u16)h; lv.z = (u16)f2b(f[2] - b2f(h));
    h = f2b(f[3]); hv.w = (u16)h; lv.w = (u16)f2b(f[3] - b2f(h));
    ((ushort4*)hi)[idx] = hv;
    ((ushort4*)lo)[idx] = lv;
}

// ---------------------------------------------------------------------------
// All 5 weights [512,512] -> transposed bf16 hi/lo planes, one dispatch.
// ---------------------------------------------------------------------------
__global__ __launch_bounds__(256) void wconv5(
    const float* __restrict__ Wq, const float* __restrict__ Wk,
    const float* __restrict__ Wv, const float* __restrict__ W1,
    const float* __restrict__ W2, u16* __restrict__ planes)
{
    __shared__ float T[32][33];
    const int wsel = blockIdx.z;
    const float* W = (wsel == 0) ? Wq : (wsel == 1) ? Wk : (wsel == 2) ? Wv
                   : (wsel == 3) ? W1 : W2;
    u16* thi = planes + (size_t)wsel * 2 * DM * DM;
    u16* tlo = thi + (size_t)DM * DM;
    const int tx = threadIdx.x & 31, ty = threadIdx.x >> 5;
    const int n0 = blockIdx.x * 32, k0 = blockIdx.y * 32;
#pragma unroll
    for (int p = 0; p < 4; ++p) {
        int r = ty + p * 8;
        T[r][tx] = W[(size_t)(k0 + r) * DM + n0 + tx];
    }
    __syncthreads();
#pragma unroll
    for (int p = 0; p < 4; ++p) {
        int rr = ty + p * 8;
        float val = T[tx][rr];                       // = W[k0+tx][n0+rr]
        unsigned h = f2b(val);
        size_t off = (size_t)(n0 + rr) * DM + k0 + tx;
        thi[off] = (u16)h;
        tlo[off] = (u16)f2b(val - b2f(h));
    }
}

// ---------------------------------------------------------------------------
// C[8192,512] = act((Ahi+Alo) @ (Bhi+Blo)^T + bias)*scale (+R)
// v2: 64x64 tile (grid 128x8 = 1024 blocks = 4/CU), BK=64, 4 waves x (2x2
// of 16x16x32 MFMA). LDS stride 72 u16 (144 B = 16B-aligned, 2-way only).
// OUTMODE: 0 = fp32 (+R), 1 = bf16 hi+lo planes, 2 = bf16 hi only.
// ---------------------------------------------------------------------------
template<int SPLIT, int RELU, int OUTMODE>
__global__ __launch_bounds__(256, 4) void mm512(
    const u16* __restrict__ Ah_g, const u16* __restrict__ Al_g,
    const u16* __restrict__ Bh_g, const u16* __restrict__ Bl_g,
    const float* __restrict__ bias, const float* __restrict__ R,
    float scale, float* __restrict__ outF,
    u16* __restrict__ outHi, u16* __restrict__ outLo)
{
    __shared__ u16 Ah[64 * 72], Bh[64 * 72];
    __shared__ u16 Al[SPLIT ? 64 * 72 : 8], Bl[SPLIT ? 64 * 72 : 8];
    const int tid = threadIdx.x, lane = tid & 63, w = tid >> 6;
    const int wr = (w >> 1) * 32, wc = (w & 1) * 32;
    const int ml = lane & 15, q8 = (lane >> 4) * 8, q4 = (lane >> 4) * 4;
    const int row0 = blockIdx.x * 64, col0 = blockIdx.y * 64;
    const int sr = tid >> 2, sc = (tid & 3) * 8;

    f32x4 acc[2][2];
#pragma unroll
    for (int i = 0; i < 2; ++i)
#pragma unroll
        for (int j = 0; j < 2; ++j) acc[i][j] = {0.f, 0.f, 0.f, 0.f};

    for (int k0 = 0; k0 < DM; k0 += 64) {
        const size_t ra = (size_t)(row0 + sr) * DM + k0 + sc;
        const size_t rb = (size_t)(col0 + sr) * DM + k0 + sc;
        *(uint4*)&Ah[sr * 72 + sc]      = *(const uint4*)&Ah_g[ra];
        *(uint4*)&Ah[sr * 72 + sc + 32] = *(const uint4*)&Ah_g[ra + 32];
        *(uint4*)&Bh[sr * 72 + sc]      = *(const uint4*)&Bh_g[rb];
        *(uint4*)&Bh[sr * 72 + sc + 32] = *(const uint4*)&Bh_g[rb + 32];
        if (SPLIT) {
            *(uint4*)&Al[sr * 72 + sc]      = *(const uint4*)&Al_g[ra];
            *(uint4*)&Al[sr * 72 + sc + 32] = *(const uint4*)&Al_g[ra + 32];
            *(uint4*)&Bl[sr * 72 + sc]      = *(const uint4*)&Bl_g[rb];
            *(uint4*)&Bl[sr * 72 + sc + 32] = *(const uint4*)&Bl_g[rb + 32];
        }
        __syncthreads();
#pragma unroll
        for (int kk = 0; kk < 64; kk += 32) {
            bf16x8 a_h[2], b_h[2], a_l[2], b_l[2];
#pragma unroll
            for (int i = 0; i < 2; ++i) {
                a_h[i] = *(const bf16x8*)&Ah[(wr + i * 16 + ml) * 72 + kk + q8];
                b_h[i] = *(const bf16x8*)&Bh[(wc + i * 16 + ml) * 72 + kk + q8];
                if (SPLIT) {
                    a_l[i] = *(const bf16x8*)&Al[(wr + i * 16 + ml) * 72 + kk + q8];
                    b_l[i] = *(const bf16x8*)&Bl[(wc + i * 16 + ml) * 72 + kk + q8];
                }
            }
#pragma unroll
            for (int i = 0; i < 2; ++i)
#pragma unroll
                for (int j = 0; j < 2; ++j) {
                    acc[i][j] = MFMA_B16(a_h[i], b_h[j], acc[i][j]);
                    if (SPLIT) {
                        acc[i][j] = MFMA_B16(a_h[i], b_l[j], acc[i][j]);
                        acc[i][j] = MFMA_B16(a_l[i], b_h[j], acc[i][j]);
                        acc[i][j] = MFMA_B16(a_l[i], b_l[j], acc[i][j]);
                    }
                }
        }
        __syncthreads();
    }

    float bcol[2];
#pragma unroll
    for (int j = 0; j < 2; ++j) bcol[j] = bias[col0 + wc + j * 16 + ml];
#pragma unroll
    for (int i = 0; i < 2; ++i)
#pragma unroll
        for (int j = 0; j < 2; ++j)
#pragma unroll
            for (int r = 0; r < 4; ++r) {
                int gm = row0 + wr + i * 16 + q4 + r;
                int gn = col0 + wc + j * 16 + ml;
                float t = acc[i][j][r] + bcol[j];
                if (RELU) t = fmaxf(t, 0.f);
                t *= scale;
                size_t off = (size_t)gm * DM + gn;
                if (OUTMODE == 0) {
                    if (R) t += R[off];
                    outF[off] = t;
                } else if (OUTMODE == 1) {
                    unsigned hb2 = f2b(t);
                    outHi[off] = (u16)hb2;
                    outLo[off] = (u16)f2b(t - b2f(hb2));
                } else {
                    outHi[off] = (u16)f2b(t);
                }
            }
}

// ---------------------------------------------------------------------------
// FUSED attention middle, v4: scores in registers. Window probe (1 barrier
// per iter, dbl-buffered counts) brackets count into [32,64]; extraction via
// LDS atomic append (order-free); per-wave value-seeded micro-bisect to
// exact 32; threshold-shifted softmax; float2-paired PV with 16-wide batch.
// ---------------------------------------------------------------------------
__global__ __launch_bounds__(256, 4) void attn_fused(
    const u16* __restrict__ qhi, const u16* __restrict__ qlo,
    const u16* __restrict__ khi, const u16* __restrict__ klo,
    const u16* __restrict__ vhi, u16* __restrict__ ao)
{
    __shared__ u16 Qh[16 * QSTR], Ql[16 * QSTR];
    __shared__ float statS[4][16], statQ[4][16];
    __shared__ int   cntW[2][4][16];
    __shared__ float2 pbuf[16 * PCAP];
    __shared__ int   pcnt[16];
    __shared__ unsigned loU[16], hiU[16];

    const int tid = threadIdx.x, lane = tid & 63, w = tid >> 6;
    const int ml = lane & 15, quad = lane >> 4, q8 = quad * 8;
    const int hb = blockIdx.y, h = hb >> 3, b = hb & 7;
    const int r0 = blockIdx.x * 16;

    // ---- stage Q (16 rows x 64 dims, hi+lo planes) ----
    {
        int t2 = tid & 127, m = t2 >> 3, k8 = (t2 & 7) * 8;
        const u16* sp = (tid < 128) ? qhi : qlo;
        u16* dst = (tid < 128) ? Qh : Ql;
        *(uint4*)&dst[m * QSTR + k8] =
            *(const uint4*)&sp[((size_t)(b * NSQ + r0 + m)) * DM + h * HDIM + k8];
    }
    if (tid < 16) pcnt[tid] = 0;
    __syncthreads();

    bf16x8 a_h0 = *(const bf16x8*)&Qh[ml * QSTR + q8];
    bf16x8 a_h1 = *(const bf16x8*)&Qh[ml * QSTR + 32 + q8];
    bf16x8 a_l0 = *(const bf16x8*)&Ql[ml * QSTR + q8];
    bf16x8 a_l1 = *(const bf16x8*)&Ql[ml * QSTR + 32 + q8];

    // ---- phase 1: scores into registers ----
    const u16* khp = khi + ((size_t)(b * NSQ + w * 256 + ml)) * DM + h * HDIM + q8;
    const u16* klp = klo + ((size_t)(b * NSQ + w * 256 + ml)) * DM + h * HDIM + q8;

    f32x4 acc[16];
#pragma unroll
    for (int t = 0; t < 16; ++t) {
        bf16x8 bh0 = *(const bf16x8*)(khp);
        bf16x8 bh1 = *(const bf16x8*)(khp + 32);
        bf16x8 bl0 = *(const bf16x8*)(klp);
        bf16x8 bl1 = *(const bf16x8*)(klp + 32);
        f32x4 a0 = {0.f, 0.f, 0.f, 0.f}, a1 = {0.f, 0.f, 0.f, 0.f};
        a0 = MFMA_B16(a_h0, bh0, a0);
        a0 = MFMA_B16(a_h1, bh1, a0);
        a0 = MFMA_B16(a_l0, bh0, a0);
        a0 = MFMA_B16(a_l1, bh1, a0);
        a1 = MFMA_B16(a_h0, bl0, a1);
        a1 = MFMA_B16(a_h1, bl1, a1);
        a1 = MFMA_B16(a_l0, bl0, a1);
        a1 = MFMA_B16(a_l1, bl1, a1);
        acc[t] = a0 + a1;
        khp += 16 * DM;
        klp += 16 * DM;
    }
    // acc[t][r] = S[row = quad*4 + r][col = w*256 + t*16 + ml]

    // ---- stats: mu/sigma per row ----
    float s1[4] = {0.f, 0.f, 0.f, 0.f}, s2[4] = {0.f, 0.f, 0.f, 0.f};
#pragma unroll
    for (int t = 0; t < 16; ++t)
#pragma unroll
        for (int r = 0; r < 4; ++r) {
            float v = acc[t][r];
            s1[r] += v;
            s2[r] = fmaf(v, v, s2[r]);
        }
#pragma unroll
    for (int off = 8; off; off >>= 1)
#pragma unroll
        for (int r = 0; r < 4; ++r) {
            s1[r] += __shfl_xor(s1[r], off);
            s2[r] += __shfl_xor(s2[r], off);
        }
    if (ml == 0)
#pragma unroll
        for (int r = 0; r < 4; ++r) {
            statS[w][quad * 4 + r] = s1[r];
            statQ[w][quad * 4 + r] = s2[r];
        }
    __syncthreads();

    float mu[4], sg[4], lo_f[4], hi_f[4];
    unsigned lo_u[4], hi_u[4];
    int clo[4];
#pragma unroll
    for (int r = 0; r < 4; ++r) {
        int row = quad * 4 + r;
        float S = statS[0][row] + statS[1][row] + statS[2][row] + statS[3][row];
        float Q = statQ[0][row] + statQ[1][row] + statQ[2][row] + statQ[3][row];
        mu[r] = S * (1.f / 1024.f);
        sg[r] = sqrtf(fmaxf(Q * (1.f / 1024.f) - mu[r] * mu[r], 0.f)) + 1e-20f;
        // Chebyshev: #{x >= mu+8s} <= 16 < 32 and #{x <= mu-8s} <= 16
        lo_f[r] = mu[r] - 8.f * sg[r];
        hi_f[r] = mu[r] + 8.f * sg[r];
        lo_u[r] = ordu(lo_f[r]);
        hi_u[r] = ordu(hi_f[r]);
        clo[r] = 1024;
    }

    // ---- lockstep WINDOW probe (1 barrier/iter, double-buffered counts) ----
    int done = 0;
    for (int iter = 0; iter < 24; ++iter) {
        float mid_f[4]; unsigned mid_u[4];
#pragma unroll
        for (int r = 0; r < 4; ++r) {
            if (!((done >> r) & 1)) {
                float fr; unsigned um;
                if (iter == 0)      fr = mu[r] + 1.70f * sg[r];
                else if (iter == 1) fr = mu[r] + ((clo[r] == 1024) ? 1.38f : 2.15f) * sg[r];
                else {
                    um = lo_u[r] + ((hi_u[r] - lo_u[r]) >> 1);
                    fr = iordu(um); mid_u[r] = um; mid_f[r] = fr;
                    continue;
                }
                um = ordu(fr);
                if (um <= lo_u[r] || um >= hi_u[r]) {
                    um = lo_u[r] + ((hi_u[r] - lo_u[r]) >> 1);
                    fr = iordu(um);
                }
                mid_u[r] = um; mid_f[r] = fr;
            } else { mid_u[r] = lo_u[r]; mid_f[r] = lo_f[r]; }
        }
        int c[4] = {0, 0, 0, 0};
#pragma unroll
        for (int t = 0; t < 16; ++t)
#pragma unroll
            for (int r = 0; r < 4; ++r) c[r] += (acc[t][r] > mid_f[r]) ? 1 : 0;
#pragma unroll
        for (int off = 8; off; off >>= 1)
#pragma unroll
            for (int r = 0; r < 4; ++r) c[r] += __shfl_xor(c[r], off);
        const int buf = iter & 1;
        if (ml == 0)
#pragma unroll
            for (int r = 0; r < 4; ++r) cntW[buf][w][quad * 4 + r] = c[r];
        __syncthreads();
        int tot[4];
#pragma unroll
        for (int r = 0; r < 4; ++r) {
            int row = quad * 4 + r;
            tot[r] = cntW[buf][0][row] + cntW[buf][1][row]
                   + cntW[buf][2][row] + cntW[buf][3][row];
        }
#pragma unroll
        for (int r = 0; r < 4; ++r) {
            if (!((done >> r) & 1)) {
                if (tot[r] >= TOPK) {
                    lo_u[r] = mid_u[r]; lo_f[r] = mid_f[r]; clo[r] = tot[r];
                    if (tot[r] <= PCAP) done |= 1 << r;    // window hit
                } else {
                    hi_u[r] = mid_u[r]; hi_f[r] = mid_f[r];
                }
                if (hi_u[r] - lo_u[r] <= 1u) done |= 1 << r;
            }
        }
        if (__all(done == 15)) break;
    }

    if (w == 0 && ml == 0)
#pragma unroll
        for (int r = 0; r < 4; ++r) {
            loU[quad * 4 + r] = lo_u[r];
            hiU[quad * 4 + r] = hi_u[r];
        }

    // ---- extraction: LDS atomic append (slot order irrelevant) ----
#pragma unroll
    for (int t = 0; t < 16; ++t)
#pragma unroll
        for (int r = 0; r < 4; ++r) {
            if (acc[t][r] > lo_f[r]) {
                int row = quad * 4 + r;
                int s = atomicAdd(&pcnt[row], 1);
                if (s < PCAP)
                    pbuf[row * PCAP + s] =
                        make_float2(acc[t][r], __int_as_float(w * 256 + t * 16 + ml));
            }
        }
    __syncthreads();

    // ---- finale per wave (rows w*4..w*4+3): micro-bisect to exact 32,
    //      tie-prune, softmax (threshold shift), compact, batched PV.
    const u16* vb = vhi + ((size_t)b * NSQ) * DM + h * HDIM + lane;
    for (int rr = 0; rr < 4; ++rr) {
        const int row = w * 4 + rr;
        int n = pcnt[row];
        if (n > PCAP) n = PCAP;
        float2 pr = (lane < n) ? pbuf[row * PCAP + lane] : make_float2(0.f, 0.f);
        float val = pr.x;
        int   col = __float_as_int(pr.y);
        unsigned uv = (lane < n) ? ordu(val) : 0u;

        // micro-bisect: value-space midpoints (uint fallback alternating)
        unsigned blo = loU[row], bhi = hiU[row];
        int it = 0;
        while (bhi - blo > 1u) {
            unsigned um;
            if (it & 1) um = blo + ((bhi - blo) >> 1);
            else {
                um = ordu(0.5f * (iordu(blo) + iordu(bhi)));
                if (um <= blo || um >= bhi) um = blo + ((bhi - blo) >> 1);
            }
            ++it;
            int c = __popcll(__ballot(uv > um));
            if (c >= TOPK) { blo = um; if (c == TOPK) break; }
            else bhi = um;
        }
        bool sel = uv > blo;
        int excess = __popcll(__ballot(sel)) - TOPK;
        while (excess > 0) {        // ties at boundary (rare): drop largest cols
            int mycol = (sel && uv == blo + 1u) ? col : -1;
            int cmx = mycol;
#pragma unroll
            for (int off = 32; off; off >>= 1) cmx = max(cmx, __shfl_xor(cmx, off));
            if (sel && mycol >= 0 && col == cmx) sel = false;
            excess--;
        }

        // softmax with threshold shift (mathematically identical to max-shift)
        float mshift = iordu(blo);
        float e = sel ? __expf(val - mshift) : 0.f;
        float s = e;
#pragma unroll
        for (int off = 32; off; off >>= 1) s += __shfl_xor(s, off);
        float p = e * (1.f / s);

        // compact selected 32 to slots 0..31 (wave-local; lgkm orders wr->rd)
        unsigned long long bm = __ballot(sel);
        int slot = __popcll(bm & ((1ull << lane) - 1ull));
        if (sel) pbuf[row * PCAP + slot] = make_float2(p, __int_as_float(col));

        float accv = 0.f;
#pragma unroll
        for (int t0 = 0; t0 < TOPK; t0 += 16) {
            float pp[16]; int cc[16]; u16 vv[16];
#pragma unroll
            for (int j = 0; j < 16; ++j) {
                float2 pc = pbuf[row * PCAP + t0 + j];
                pp[j] = pc.x; cc[j] = __float_as_int(pc.y);
            }
#pragma unroll
            for (int j = 0; j < 16; ++j) vv[j] = vb[(size_t)cc[j] * DM];
#pragma unroll
            for (int j = 0; j < 16; ++j) accv = fmaf(pp[j], b2f(vv[j]), accv);
        }
        ao[((size_t)(b * NSQ + r0 + row)) * DM + h * HDIM + lane] = (u16)f2b(accv);
    }
}

// ---------------------------------------------------------------------------
// LayerNorm: out = LN(a [+ bf16 addb]) * g + be; optional fp32 + bf16-hi outs
// ---------------------------------------------------------------------------
__global__ __launch_bounds__(256) void ln_fused(
    const float* __restrict__ a, const u16* __restrict__ addb,
    const float* __restrict__ g, const float* __restrict__ be,
    float* __restrict__ outF, u16* __restrict__ outHi)
{
    __shared__ float red[4][2];
    const int row = blockIdx.x, tid = threadIdx.x, w = tid >> 6;
    float2 v = ((const float2*)(a + (size_t)row * DM))[tid];
    if (addb) {
        ushort2 ab = ((const ushort2*)(addb + (size_t)row * DM))[tid];
        v.x += b2f(ab.x); v.y += b2f(ab.y);
    }
    float s = v.x + v.y, q = v.x * v.x + v.y * v.y;
#pragma unroll
    for (int o = 32; o; o >>= 1) { s += __shfl_xor(s, o); q += __shfl_xor(q, o); }
    if ((tid & 63) == 0) { red[w][0] = s; red[w][1] = q; }
    __syncthreads();
    float S = red[0][0] + red[1][0] + red[2][0] + red[3][0];
    float Q = red[0][1] + red[1][1] + red[2][1] + red[3][1];
    float mu = S * (1.f / DM);
    float var = Q * (1.f / DM) - mu * mu;
    float rs = rsqrtf(var + 1e-5f);
    float2 gv = ((const float2*)g)[tid];
    float2 bv = ((const float2*)be)[tid];
    float2 o;
    o.x = (v.x - mu) * rs * gv.x + bv.x;
    o.y = (v.y - mu) * rs * gv.y + bv.y;
    if (outF) ((float2*)(outF + (size_t)row * DM))[tid] = o;
    if (outHi) {
        ushort2 hv; hv.x = (u16)f2b(o.x); hv.y = (u16)f2b(o.y);
        ((ushort2*)(outHi + (size_t)row * DM))[tid] = hv;
    }
}

// ---------------------------------------------------------------------------
extern "C" void kernel_launch(void* const* d_in, const int* in_sizes, int n_in,
                              void* d_out, int out_size, void* d_ws, size_t ws_size,
                              hipStream_t stream) {
    const float* src = (const float*)d_in[0];
    const float* tgt = (const float*)d_in[1];
    const float* Wq  = (const float*)d_in[2];
    const float* bq  = (const float*)d_in[3];
    const float* Wk  = (const float*)d_in[4];
    const float* bk  = (const float*)d_in[5];
    const float* Wv  = (const float*)d_in[6];
    const float* bv  = (const float*)d_in[7];
    const float* W1  = (const float*)d_in[8];
    const float* b1  = (const float*)d_in[9];
    const float* W2  = (const float*)d_in[10];
    const float* b2  = (const float*)d_in[11];
    const float* g1  = (const float*)d_in[12];
    const float* be1 = (const float*)d_in[13];
    const float* g2  = (const float*)d_in[14];
    const float* be2 = (const float*)d_in[15];

    // workspace map (MB offsets). Total footprint: 136 MB.
    const size_t WPLANE = (size_t)DM * DM;
    u16* planes = (u16*)d_ws;                    // 10 x 512 KB = 5 MB
    auto wh = [&](int i) { return planes + (size_t)i * 2 * WPLANE; };
    auto wl = [&](int i) { return planes + (size_t)i * 2 * WPLANE + WPLANE; };
    auto at = [&](size_t mb) { return (char*)d_ws + (mb << 20); };
    u16* Thi = (u16*)at(8);   u16* Tlo = (u16*)at(16);
    u16* Shi = (u16*)at(24);  u16* Slo = (u16*)at(32);
    u16* qhi = (u16*)at(40);  u16* qlo = (u16*)at(48);
    u16* khi = (u16*)at(56);  u16* klo = (u16*)at(64);
    u16* vhi = (u16*)at(72);
    u16* aob = (u16*)at(80);
    float* xb = (float*)at(88);                  // 16 MB fp32
    u16* xhi = (u16*)at(104);
    u16* hhi = (u16*)at(112);
    float* f2 = (float*)at(120);                 // 16 MB fp32

    dim3 blk(256);
    dim3 gmm(128, 8);
    const float qscale = 0.04419417382415922f;   // 1/sqrt(512)

    wconv5<<<dim3(16, 16, 5), blk, 0, stream>>>(Wq, Wk, Wv, W1, W2, planes);
    conv2<<<dim3(4096, 2), blk, 0, stream>>>(tgt, src, Thi, Tlo, Shi, Slo);

    mm512<1, 0, 1><<<gmm, blk, 0, stream>>>(Thi, Tlo, wh(0), wl(0), bq, nullptr,
                                            qscale, nullptr, qhi, qlo);
    mm512<1, 0, 1><<<gmm, blk, 0, stream>>>(Shi, Slo, wh(1), wl(1), bk, nullptr,
                                            1.f, nullptr, khi, klo);
    mm512<0, 0, 2><<<gmm, blk, 0, stream>>>(Shi, nullptr, wh(2), nullptr, bv, nullptr,
                                            1.f, nullptr, vhi, nullptr);

    attn_fused<<<dim3(64, 64), blk, 0, stream>>>(qhi, qlo, khi, klo, vhi, aob);

    ln_fused<<<8192, blk, 0, stream>>>(tgt, aob, g1, be1, xb, xhi);
    mm512<0, 1, 2><<<gmm, blk, 0, stream>>>(xhi, nullptr, wh(3), nullptr, b1, nullptr,
                                            1.f, nullptr, hhi, nullptr);
    mm512<0, 0, 0><<<gmm, blk, 0, stream>>>(hhi, nullptr, wh(4), nullptr, b2, xb,
                                            1.f, f2, nullptr, nullptr);
    ln_fused<<<8192, blk, 0, stream>>>(f2, nullptr, g2, be2, (float*)d_out, nullptr);
}